// Round 3
// baseline (1709.473 us; speedup 1.0000x reference)
//
#include <hip/hip_runtime.h>
#include <math.h>

// GCN 2-layer forward on MI355X — v3.
// Replaces global CSR build (k_fill: 306us, 195MB write-amplification) with
// dst-binned edges (256 nodes/bin) via per-WG local counting sort, plus
// per-bin LDS-accumulated aggregation (ds_add_f32).
//
// Pipeline: memset cnt -> k_binA (bin edges + degree count) -> k_dinv ->
//           k_gemm1 (m1=(x@W1)*dinv) -> k_aggB (conv1 agg+relu+@W2 -> m2)
//           -> k_aggC (conv2 agg + bias + mask -> out)

constexpr int N   = 100000;
constexpr int E   = 3200000;
constexpr int FIN = 128;
constexpr int FH  = 64;

constexpr int NPB = 256;                       // nodes per bin
constexpr int NB  = (N + NPB - 1) / NPB;       // 391 bins
constexpr int K   = 12800;                     // edges per chunk
constexpr int NC  = E / K;                     // 250 chunks (exact)

// ---- pass A: per-chunk counting sort by dst-bin; also global degree count ----
__global__ __launch_bounds__(512) void k_binA(const int* __restrict__ srcA,
                                              const int* __restrict__ dstA,
                                              int* __restrict__ cnt,
                                              unsigned* __restrict__ binned,
                                              int* __restrict__ segStart,
                                              int* __restrict__ segCnt) {
  __shared__ int bc[NB];
  __shared__ int bs[NB];
  __shared__ int cur[NB];
  const int w = blockIdx.x;
  const int base = w * K;
  for (int i = threadIdx.x; i < NB; i += 512) bc[i] = 0;
  __syncthreads();
  for (int i = threadIdx.x; i < K; i += 512) {
    int d = dstA[base + i];
    atomicAdd(&bc[d >> 8], 1);
    atomicAdd(&cnt[d], 1);          // global in-degree (for dinv)
  }
  __syncthreads();
  if (threadIdx.x == 0) {           // serial exclusive scan of 391 ints
    int s = 0;
    for (int b = 0; b < NB; ++b) { bs[b] = s; s += bc[b]; }
  }
  __syncthreads();
  for (int i = threadIdx.x; i < NB; i += 512) {
    cur[i] = 0;
    segStart[w * NB + i] = base + bs[i];
    segCnt[w * NB + i]   = bc[i];
  }
  __syncthreads();
  for (int i = threadIdx.x; i < K; i += 512) {
    int s = srcA[base + i];
    int d = dstA[base + i];
    int b = d >> 8;
    int slot = base + bs[b] + atomicAdd(&cur[b], 1);   // private 51KB window: L2-resident
    binned[slot] = ((unsigned)(d & 255) << 17) | (unsigned)s;  // src<2^17, dl<2^8
  }
}

__global__ void k_dinv(const int* __restrict__ cnt, float* __restrict__ dinv) {
  int i = blockIdx.x * blockDim.x + threadIdx.x;
  if (i < N) dinv[i] = 1.0f / sqrtf((float)(cnt[i] + 1));  // +1 self-loop
}

// ---- m1[n, f] = (x[n,:] @ W1[:,f]) * dinv[n] ----
__global__ __launch_bounds__(256) void k_gemm1(const float* __restrict__ x,
                                               const float* __restrict__ W1,
                                               const float* __restrict__ dinv,
                                               float* __restrict__ m1) {
  __shared__ float W1s[FIN * FH];  // 32 KB
  for (int i = threadIdx.x; i < FIN * FH; i += 256) W1s[i] = W1[i];
  __syncthreads();
  int lane = threadIdx.x & 63;
  int w = threadIdx.x >> 6;
  for (int grp = blockIdx.x; grp * 4 < N; grp += gridDim.x) {
    int node = grp * 4 + w;
    if (node >= N) continue;
    int nu = __builtin_amdgcn_readfirstlane(node);
    const float* xr = x + (size_t)nu * FIN;
    float a0 = 0.f, a1 = 0.f, a2 = 0.f, a3 = 0.f;
#pragma unroll
    for (int k = 0; k < FIN; k += 4) {
      a0 = fmaf(xr[k + 0], W1s[(k + 0) * FH + lane], a0);
      a1 = fmaf(xr[k + 1], W1s[(k + 1) * FH + lane], a1);
      a2 = fmaf(xr[k + 2], W1s[(k + 2) * FH + lane], a2);
      a3 = fmaf(xr[k + 3], W1s[(k + 3) * FH + lane], a3);
    }
    m1[(size_t)nu * FH + lane] = ((a0 + a1) + (a2 + a3)) * dinv[nu];
  }
}

// ---- conv1: per-bin LDS accumulate + relu + fused @W2 -> m2 (pre-scaled) ----
__global__ __launch_bounds__(512) void k_aggB(const float* __restrict__ m1,
                                              const unsigned* __restrict__ binned,
                                              const int* __restrict__ segStart,
                                              const int* __restrict__ segCnt,
                                              const float* __restrict__ dinv,
                                              const float* __restrict__ b1,
                                              const float* __restrict__ W2,
                                              float* __restrict__ m2) {
  __shared__ float acc[NPB * FH];  // 64 KB -> 2 WG/CU
  const int b = blockIdx.x;
  for (int i = threadIdx.x; i < NPB * FH; i += 512) acc[i] = 0.f;
  __syncthreads();
  const int lane = threadIdx.x & 63;
  const int wv = threadIdx.x >> 6;  // 0..7
  for (int w = wv; w < NC; w += 8) {
    int st = segStart[w * NB + b];
    int cn = segCnt[w * NB + b];
    for (int bb = 0; bb < cn; bb += 64) {
      int m = min(64, cn - bb);
      int e = (lane < m) ? (int)binned[st + bb + lane] : 0;
      int j = 0;
      for (; j + 2 <= m; j += 2) {
        unsigned e0 = (unsigned)__shfl(e, j);
        unsigned e1 = (unsigned)__shfl(e, j + 1);
        float v0 = m1[(size_t)(e0 & 0x1FFFFu) * FH + lane];
        float v1 = m1[(size_t)(e1 & 0x1FFFFu) * FH + lane];
        atomicAdd(&acc[(e0 >> 17) * FH + lane], v0);
        atomicAdd(&acc[(e1 >> 17) * FH + lane], v1);
      }
      if (j < m) {
        unsigned e0 = (unsigned)__shfl(e, j);
        atomicAdd(&acc[(e0 >> 17) * FH + lane],
                  m1[(size_t)(e0 & 0x1FFFFu) * FH + lane]);
      }
    }
  }
  __syncthreads();
  // finalize 256 nodes with 8 waves
  const float b1v = b1[lane];
  const float w20 = W2[lane * 2 + 0];
  const float w21 = W2[lane * 2 + 1];
  const int nodeBase = b * NPB;
  for (int nl = wv; nl < NPB; nl += 8) {
    int node = nodeBase + nl;
    if (node >= N) break;  // uniform per wave
    float a = acc[nl * FH + lane] + m1[(size_t)node * FH + lane];  // + self-loop
    float dv = dinv[node];
    float h = fmaxf(fmaf(a, dv, b1v), 0.f);
    float p0 = h * w20;
    float p1 = h * w21;
#pragma unroll
    for (int off = 32; off; off >>= 1) {
      p0 += __shfl_xor(p0, off);
      p1 += __shfl_xor(p1, off);
    }
    if (lane == 0) {
      m2[node * 2 + 0] = p0 * dv;
      m2[node * 2 + 1] = p1 * dv;
    }
  }
}

// ---- conv2: per-bin aggregate m2 + bias + generator mask -> out ----
__global__ __launch_bounds__(256) void k_aggC(const float* __restrict__ m2,
                                              const unsigned* __restrict__ binned,
                                              const int* __restrict__ segStart,
                                              const int* __restrict__ segCnt,
                                              const float* __restrict__ dinv,
                                              const float* __restrict__ b2,
                                              const float* __restrict__ x,
                                              float* __restrict__ out) {
  __shared__ float acc2[NPB * 2];
  const int b = blockIdx.x;
  for (int i = threadIdx.x; i < NPB * 2; i += 256) acc2[i] = 0.f;
  __syncthreads();
  const int lane = threadIdx.x & 63;
  const int wv = threadIdx.x >> 6;  // 0..3
  for (int w = wv; w < NC; w += 4) {
    int st = segStart[w * NB + b];
    int cn = segCnt[w * NB + b];
    for (int bb = lane; bb < cn; bb += 64) {
      unsigned e = binned[st + bb];
      int s = (int)(e & 0x1FFFFu);
      int dl = (int)(e >> 17);
      atomicAdd(&acc2[dl * 2 + 0], m2[s * 2 + 0]);
      atomicAdd(&acc2[dl * 2 + 1], m2[s * 2 + 1]);
    }
  }
  __syncthreads();
  int node = b * NPB + threadIdx.x;
  if (threadIdx.x < NPB && node < N) {
    float dv = dinv[node];
    float o0 = (acc2[threadIdx.x * 2 + 0] + m2[node * 2 + 0]) * dv + b2[0];
    float o1 = (acc2[threadIdx.x * 2 + 1] + m2[node * 2 + 1]) * dv + b2[1];
    float msk = (x[(size_t)node * FIN] == 1.0f) ? 1.0f : 0.0f;
    out[node * 2 + 0] = o0 * msk;
    out[node * 2 + 1] = o1 * msk;
  }
}

extern "C" void kernel_launch(void* const* d_in, const int* in_sizes, int n_in,
                              void* d_out, int out_size, void* d_ws, size_t ws_size,
                              hipStream_t stream) {
  const float* x   = (const float*)d_in[0];
  const int*   ei  = (const int*)d_in[1];  // int32 [2, E] flat
  const float* W1  = (const float*)d_in[2];
  const float* b1  = (const float*)d_in[3];
  const float* W2  = (const float*)d_in[4];
  const float* b2  = (const float*)d_in[5];
  float*       out = (float*)d_out;

  char* w = (char*)d_ws;
  auto alloc = [&](size_t bytes) -> char* {
    char* p = w;
    w += (bytes + 255) & ~(size_t)255;
    return p;
  };
  int*      cnt      = (int*)alloc((size_t)N * 4);
  float*    dinv     = (float*)alloc((size_t)N * 4);
  float*    m1       = (float*)alloc((size_t)N * FH * 4);
  float*    m2       = (float*)alloc((size_t)N * 2 * 4);
  unsigned* binned   = (unsigned*)alloc((size_t)E * 4);
  int*      segStart = (int*)alloc((size_t)NC * NB * 4);
  int*      segCnt   = (int*)alloc((size_t)NC * NB * 4);

  const int* srcA = ei;      // edge_index[0]
  const int* dstA = ei + E;  // edge_index[1]

  hipMemsetAsync(cnt, 0, (size_t)N * 4, stream);
  k_binA<<<dim3(NC), dim3(512), 0, stream>>>(srcA, dstA, cnt, binned, segStart, segCnt);
  k_dinv<<<dim3((N + 255) / 256), dim3(256), 0, stream>>>(cnt, dinv);
  k_gemm1<<<dim3(1024), dim3(256), 0, stream>>>(x, W1, dinv, m1);
  k_aggB<<<dim3(NB), dim3(512), 0, stream>>>(m1, binned, segStart, segCnt, dinv, b1, W2, m2);
  k_aggC<<<dim3(NB), dim3(256), 0, stream>>>(m2, binned, segStart, segCnt, dinv, b2, x, out);
}

// Round 4
// 374.763 us; speedup vs baseline: 4.5615x; 4.5615x over previous
//
#include <hip/hip_runtime.h>
#include <hip/hip_bf16.h>
#include <math.h>

// GCN 2-layer forward on MI355X — v4.
// binA (L2-local dst-binning) -> scan (rowptr,dinv) -> fill2 (bin-local CSR
// build, no write amplification) -> gemm1 (m1=(x@W1)*dinv, bf16) ->
// agg1 (wave-per-node gather + relu + @W2) -> agg2 (light gather + mask).

constexpr int N   = 100000;
constexpr int E   = 3200000;
constexpr int FIN = 128;
constexpr int FH  = 64;

constexpr int NPB = 256;                      // nodes per bin
constexpr int NB  = (N + NPB - 1) / NPB;      // 391 bins
constexpr int K   = 12800;                    // edges per chunk
constexpr int NC  = E / K;                    // 250 chunks (exact)

#define SCAN_BS 1024
constexpr int NB_SCAN = (N + SCAN_BS - 1) / SCAN_BS;  // 98

// ---- pass A: per-chunk counting sort by dst-bin; also global degree count ----
__global__ __launch_bounds__(512) void k_binA(const int* __restrict__ srcA,
                                              const int* __restrict__ dstA,
                                              int* __restrict__ cnt,
                                              unsigned* __restrict__ binned,
                                              int* __restrict__ segStart,
                                              int* __restrict__ segCnt) {
  __shared__ int bc[NB];
  __shared__ int bs[NB];
  __shared__ int cur[NB];
  const int w = blockIdx.x;
  const int base = w * K;
  for (int i = threadIdx.x; i < NB; i += 512) bc[i] = 0;
  __syncthreads();
  for (int i = threadIdx.x; i < K; i += 512) {
    int d = dstA[base + i];
    atomicAdd(&bc[d >> 8], 1);
    atomicAdd(&cnt[d], 1);          // global in-degree (for dinv)
  }
  __syncthreads();
  if (threadIdx.x == 0) {           // serial exclusive scan of 391 ints
    int s = 0;
    for (int b = 0; b < NB; ++b) { bs[b] = s; s += bc[b]; }
  }
  __syncthreads();
  for (int i = threadIdx.x; i < NB; i += 512) {
    cur[i] = 0;
    segStart[w * NB + i] = base + bs[i];
    segCnt[w * NB + i]   = bc[i];
  }
  __syncthreads();
  for (int i = threadIdx.x; i < K; i += 512) {
    int s = srcA[base + i];
    int d = dstA[base + i];
    int b = d >> 8;
    int slot = base + bs[b] + atomicAdd(&cur[b], 1);   // 51KB window: L2-resident
    binned[slot] = ((unsigned)(d & 255) << 17) | (unsigned)s;  // src<2^17, dl<2^8
  }
}

// ---- scan chain: cnt -> rowptr (exclusive prefix), dinv ----
__global__ void k_blocksum(const int* __restrict__ cnt, int* __restrict__ bsum) {
  __shared__ int sh[SCAN_BS];
  int i = blockIdx.x * SCAN_BS + threadIdx.x;
  sh[threadIdx.x] = (i < N) ? cnt[i] : 0;
  __syncthreads();
  for (int off = SCAN_BS / 2; off > 0; off >>= 1) {
    if (threadIdx.x < off) sh[threadIdx.x] += sh[threadIdx.x + off];
    __syncthreads();
  }
  if (threadIdx.x == 0) bsum[blockIdx.x] = sh[0];
}

__global__ void k_scanbsum(int* __restrict__ bsum) {
  if (threadIdx.x == 0 && blockIdx.x == 0) {
    int s = 0;
    for (int b = 0; b < NB_SCAN; ++b) { int v = bsum[b]; bsum[b] = s; s += v; }
  }
}

__global__ void k_scan3(const int* __restrict__ cnt, const int* __restrict__ bsum,
                        int* __restrict__ rowptr, float* __restrict__ dinv) {
  __shared__ int sh[SCAN_BS];
  int i = blockIdx.x * SCAN_BS + threadIdx.x;
  int v = (i < N) ? cnt[i] : 0;
  sh[threadIdx.x] = v;
  __syncthreads();
  for (int off = 1; off < SCAN_BS; off <<= 1) {
    int t = (threadIdx.x >= off) ? sh[threadIdx.x - off] : 0;
    __syncthreads();
    sh[threadIdx.x] += t;
    __syncthreads();
  }
  if (i < N) {
    int incl = sh[threadIdx.x] + bsum[blockIdx.x];
    rowptr[i + 1] = incl;
    if (i == 0) rowptr[0] = 0;
    dinv[i] = 1.0f / sqrtf((float)(v + 1));  // +1 self-loop, deg>=1 always
  }
}

// ---- pass B: bin-local CSR fill (writes confined to ~33KB window per WG) ----
__global__ __launch_bounds__(512) void k_fill2(const unsigned* __restrict__ binned,
                                               const int* __restrict__ segStart,
                                               const int* __restrict__ segCnt,
                                               const int* __restrict__ rowptr,
                                               int* __restrict__ csr_src) {
  __shared__ int cur[NPB];
  const int b = blockIdx.x;
  if (threadIdx.x < NPB) {
    int node = b * NPB + threadIdx.x;
    cur[threadIdx.x] = (node < N) ? rowptr[node] : 0;
  }
  __syncthreads();
  const int lane = threadIdx.x & 63;
  const int wv = threadIdx.x >> 6;  // 8 waves
  for (int w = wv; w < NC; w += 8) {
    int st = segStart[w * NB + b];
    int cn = segCnt[w * NB + b];
    for (int i = lane; i < cn; i += 64) {
      unsigned e = binned[st + i];
      int p = atomicAdd(&cur[e >> 17], 1);
      csr_src[p] = (int)(e & 0x1FFFFu);
    }
  }
}

// ---- m1[n, f] = bf16((x[n,:] @ W1[:,f]) * dinv[n]) ----
__global__ __launch_bounds__(256) void k_gemm1(const float* __restrict__ x,
                                               const float* __restrict__ W1,
                                               const float* __restrict__ dinv,
                                               __hip_bfloat16* __restrict__ m1) {
  __shared__ float W1s[FIN * FH];  // 32 KB
  for (int i = threadIdx.x; i < FIN * FH; i += 256) W1s[i] = W1[i];
  __syncthreads();
  int lane = threadIdx.x & 63;
  int w = threadIdx.x >> 6;
  for (int grp = blockIdx.x; grp * 4 < N; grp += gridDim.x) {
    int node = grp * 4 + w;
    if (node >= N) continue;
    int nu = __builtin_amdgcn_readfirstlane(node);
    const float* xr = x + (size_t)nu * FIN;
    float a0 = 0.f, a1 = 0.f, a2 = 0.f, a3 = 0.f;
#pragma unroll
    for (int k = 0; k < FIN; k += 4) {
      a0 = fmaf(xr[k + 0], W1s[(k + 0) * FH + lane], a0);
      a1 = fmaf(xr[k + 1], W1s[(k + 1) * FH + lane], a1);
      a2 = fmaf(xr[k + 2], W1s[(k + 2) * FH + lane], a2);
      a3 = fmaf(xr[k + 3], W1s[(k + 3) * FH + lane], a3);
    }
    m1[(size_t)nu * FH + lane] = __float2bfloat16(((a0 + a1) + (a2 + a3)) * dinv[nu]);
  }
}

// ---- conv1: wave-per-node CSR gather (4-deep) + relu + fused @W2 -> m2 ----
__global__ __launch_bounds__(256) void k_agg1(const __hip_bfloat16* __restrict__ m1,
                                              const int* __restrict__ rowptr,
                                              const int* __restrict__ csr_src,
                                              const float* __restrict__ dinv,
                                              const float* __restrict__ b1,
                                              const float* __restrict__ W2,
                                              float* __restrict__ m2) {
  int node = blockIdx.x * 4 + (threadIdx.x >> 6);
  if (node >= N) return;
  int lane = threadIdx.x & 63;
  int nu = __builtin_amdgcn_readfirstlane(node);
  int start = __builtin_amdgcn_readfirstlane(rowptr[nu]);
  int end   = __builtin_amdgcn_readfirstlane(rowptr[nu + 1]);
  float acc = __bfloat162float(m1[(size_t)nu * FH + lane]);  // self-loop
  for (int base = start; base < end; base += 64) {
    int m = min(64, end - base);
    int sv = (lane < m) ? csr_src[base + lane] : 0;  // one coalesced id read
    float a0 = 0.f, a1 = 0.f, a2 = 0.f, a3 = 0.f;
    int j = 0;
    for (; j + 4 <= m; j += 4) {
      int s0 = __shfl(sv, j);
      int s1 = __shfl(sv, j + 1);
      int s2 = __shfl(sv, j + 2);
      int s3 = __shfl(sv, j + 3);
      a0 += __bfloat162float(m1[(size_t)s0 * FH + lane]);
      a1 += __bfloat162float(m1[(size_t)s1 * FH + lane]);
      a2 += __bfloat162float(m1[(size_t)s2 * FH + lane]);
      a3 += __bfloat162float(m1[(size_t)s3 * FH + lane]);
    }
    for (; j < m; ++j)
      a0 += __bfloat162float(m1[(size_t)__shfl(sv, j) * FH + lane]);
    acc += (a0 + a1) + (a2 + a3);
  }
  float dv = dinv[nu];
  float h = fmaxf(fmaf(acc, dv, b1[lane]), 0.f);
  float p0 = h * W2[lane * 2 + 0];
  float p1 = h * W2[lane * 2 + 1];
#pragma unroll
  for (int off = 32; off; off >>= 1) {
    p0 += __shfl_xor(p0, off);
    p1 += __shfl_xor(p1, off);
  }
  if (lane == 0) {
    m2[nu * 2 + 0] = p0 * dv;
    m2[nu * 2 + 1] = p1 * dv;
  }
}

// ---- conv2: wave-per-node light gather + bias + generator mask ----
__global__ __launch_bounds__(256) void k_agg2(const float* __restrict__ m2,
                                              const int* __restrict__ rowptr,
                                              const int* __restrict__ csr_src,
                                              const float* __restrict__ dinv,
                                              const float* __restrict__ b2,
                                              const float* __restrict__ x,
                                              float* __restrict__ out) {
  int node = blockIdx.x * 4 + (threadIdx.x >> 6);
  if (node >= N) return;
  int lane = threadIdx.x & 63;
  int nu = __builtin_amdgcn_readfirstlane(node);
  int start = __builtin_amdgcn_readfirstlane(rowptr[nu]);
  int end   = __builtin_amdgcn_readfirstlane(rowptr[nu + 1]);
  float a0 = 0.f, a1 = 0.f;
  for (int e = start + lane; e < end; e += 64) {
    int s = csr_src[e];
    a0 += m2[s * 2 + 0];
    a1 += m2[s * 2 + 1];
  }
#pragma unroll
  for (int off = 32; off; off >>= 1) {
    a0 += __shfl_xor(a0, off);
    a1 += __shfl_xor(a1, off);
  }
  if (lane == 0) {
    a0 += m2[nu * 2 + 0];  // self-loop
    a1 += m2[nu * 2 + 1];
    float dv = dinv[nu];
    float o0 = a0 * dv + b2[0];
    float o1 = a1 * dv + b2[1];
    float msk = (x[(size_t)nu * FIN] == 1.0f) ? 1.0f : 0.0f;
    out[nu * 2 + 0] = o0 * msk;
    out[nu * 2 + 1] = o1 * msk;
  }
}

extern "C" void kernel_launch(void* const* d_in, const int* in_sizes, int n_in,
                              void* d_out, int out_size, void* d_ws, size_t ws_size,
                              hipStream_t stream) {
  const float* x   = (const float*)d_in[0];
  const int*   ei  = (const int*)d_in[1];  // int32 [2, E] flat
  const float* W1  = (const float*)d_in[2];
  const float* b1  = (const float*)d_in[3];
  const float* W2  = (const float*)d_in[4];
  const float* b2  = (const float*)d_in[5];
  float*       out = (float*)d_out;

  char* w = (char*)d_ws;
  auto alloc = [&](size_t bytes) -> char* {
    char* p = w;
    w += (bytes + 255) & ~(size_t)255;
    return p;
  };
  int*            cnt      = (int*)alloc((size_t)N * 4);
  int*            rowptr   = (int*)alloc((size_t)(N + 1) * 4);
  float*          dinv     = (float*)alloc((size_t)N * 4);
  int*            bsum     = (int*)alloc((size_t)NB_SCAN * 4);
  unsigned*       binned   = (unsigned*)alloc((size_t)E * 4);
  int*            segStart = (int*)alloc((size_t)NC * NB * 4);
  int*            segCnt   = (int*)alloc((size_t)NC * NB * 4);
  int*            csr_src  = (int*)alloc((size_t)E * 4);
  __hip_bfloat16* m1       = (__hip_bfloat16*)alloc((size_t)N * FH * 2);
  float*          m2       = (float*)alloc((size_t)N * 2 * 4);

  const int* srcA = ei;      // edge_index[0]
  const int* dstA = ei + E;  // edge_index[1]

  hipMemsetAsync(cnt, 0, (size_t)N * 4, stream);
  k_binA<<<dim3(NC), dim3(512), 0, stream>>>(srcA, dstA, cnt, binned, segStart, segCnt);
  k_blocksum<<<dim3(NB_SCAN), dim3(SCAN_BS), 0, stream>>>(cnt, bsum);
  k_scanbsum<<<dim3(1), dim3(64), 0, stream>>>(bsum);
  k_scan3<<<dim3(NB_SCAN), dim3(SCAN_BS), 0, stream>>>(cnt, bsum, rowptr, dinv);
  k_fill2<<<dim3(NB), dim3(512), 0, stream>>>(binned, segStart, segCnt, rowptr, csr_src);
  k_gemm1<<<dim3(1024), dim3(256), 0, stream>>>(x, W1, dinv, m1);
  k_agg1<<<dim3((N + 3) / 4), dim3(256), 0, stream>>>(m1, rowptr, csr_src, dinv, b1, W2, m2);
  k_agg2<<<dim3((N + 3) / 4), dim3(256), 0, stream>>>(m2, rowptr, csr_src, dinv, b2, x, out);
}

// Round 5
// 333.648 us; speedup vs baseline: 5.1236x; 1.1232x over previous
//
#include <hip/hip_runtime.h>
#include <hip/hip_bf16.h>
#include <math.h>

// GCN 2-layer forward on MI355X — v5.
// v4 post-mortem: k_binA's 3.2M global atomicAdd(cnt) was 155us (write-amp +
// latency). v5: bin WITHOUT global atomics; degrees/rowptr derived per-bin in
// LDS (k_fill3). CSR is bin-major dense via binBase scan.
// Pipeline: binA2 -> binTot -> binScan -> fill3 (rowptr+dinv+csr) ->
//           gemm1 (m1=(x@W1)*dinv bf16) -> agg1 (gather+relu+@W2) -> agg2.

constexpr int N   = 100000;
constexpr int E   = 3200000;
constexpr int FIN = 128;
constexpr int FH  = 64;

constexpr int NPB = 256;                      // nodes per bin
constexpr int NB  = (N + NPB - 1) / NPB;      // 391 bins
constexpr int K   = 6400;                     // edges per chunk
constexpr int NC  = E / K;                    // 500 chunks (exact)

// ---- pass A: per-chunk counting sort by dst-bin (LDS atomics only) ----
__global__ __launch_bounds__(512) void k_binA2(const int* __restrict__ srcA,
                                               const int* __restrict__ dstA,
                                               unsigned* __restrict__ binned,
                                               int* __restrict__ segStart,
                                               int* __restrict__ segCnt) {
  __shared__ int bc[NB];
  __shared__ int bs[NB];
  __shared__ int cur[NB];
  const int w = blockIdx.x;
  const int base = w * K;
  for (int i = threadIdx.x; i < NB; i += 512) bc[i] = 0;
  __syncthreads();
  for (int i = threadIdx.x; i < K; i += 512)
    atomicAdd(&bc[dstA[base + i] >> 8], 1);
  __syncthreads();
  if (threadIdx.x == 0) {           // serial exclusive scan of 391 ints (cheap)
    int s = 0;
    for (int b = 0; b < NB; ++b) { bs[b] = s; s += bc[b]; }
  }
  __syncthreads();
  for (int i = threadIdx.x; i < NB; i += 512) {
    cur[i] = 0;
    segStart[w * NB + i] = base + bs[i];
    segCnt[w * NB + i]   = bc[i];
  }
  __syncthreads();
  for (int i = threadIdx.x; i < K; i += 512) {
    int s = srcA[base + i];
    int d = dstA[base + i];
    int b = d >> 8;
    int slot = base + bs[b] + atomicAdd(&cur[b], 1);   // 25KB window: L2-resident
    binned[slot] = ((unsigned)(d & 255) << 17) | (unsigned)s;  // src<2^17, dl<2^8
  }
}

// ---- per-bin edge totals ----
__global__ __launch_bounds__(256) void k_binTot(const int* __restrict__ segCnt,
                                                int* __restrict__ binTot) {
  __shared__ int sh[256];
  const int b = blockIdx.x;
  int s = 0;
  for (int w = threadIdx.x; w < NC; w += 256) s += segCnt[w * NB + b];
  sh[threadIdx.x] = s;
  __syncthreads();
  for (int off = 128; off; off >>= 1) {
    if (threadIdx.x < off) sh[threadIdx.x] += sh[threadIdx.x + off];
    __syncthreads();
  }
  if (threadIdx.x == 0) binTot[b] = sh[0];
}

// ---- tiny serial scan over 391 bins ----
__global__ void k_binScan(const int* __restrict__ binTot,
                          int* __restrict__ binBase, int* __restrict__ rowptr) {
  if (threadIdx.x == 0 && blockIdx.x == 0) {
    int s = 0;
    for (int b = 0; b < NB; ++b) { binBase[b] = s; s += binTot[b]; }
    binBase[NB] = s;
    rowptr[N] = s;  // == E
  }
}

// ---- per-bin: count node degrees, LDS scan -> rowptr/dinv, place csr ----
__global__ __launch_bounds__(512) void k_fill3(const unsigned* __restrict__ binned,
                                               const int* __restrict__ segStart,
                                               const int* __restrict__ segCnt,
                                               const int* __restrict__ binBase,
                                               int* __restrict__ rowptr,
                                               float* __restrict__ dinv,
                                               int* __restrict__ csr_src) {
  __shared__ int cnt_s[NPB];
  __shared__ int sh[NPB];
  __shared__ int cur[NPB];
  const int b = blockIdx.x;
  const int t = threadIdx.x;
  if (t < NPB) cnt_s[t] = 0;
  __syncthreads();
  const int lane = t & 63;
  const int wv = t >> 6;  // 8 waves
  for (int w = wv; w < NC; w += 8) {
    int st = segStart[w * NB + b];
    int cn = segCnt[w * NB + b];
    for (int i = lane; i < cn; i += 64)
      atomicAdd(&cnt_s[binned[st + i] >> 17], 1);
  }
  __syncthreads();
  int v = 0;
  if (t < NPB) { v = cnt_s[t]; sh[t] = v; }
  __syncthreads();
  for (int off = 1; off < NPB; off <<= 1) {   // Hillis-Steele inclusive
    int tv = (t < NPB && t >= off) ? sh[t - off] : 0;
    __syncthreads();
    if (t < NPB) sh[t] += tv;
    __syncthreads();
  }
  if (t < NPB) {
    int node = b * NPB + t;
    int start = binBase[b] + sh[t] - v;  // exclusive prefix
    if (node < N) {
      rowptr[node] = start;
      dinv[node] = 1.0f / sqrtf((float)(v + 1));  // +1 self-loop
    }
    cur[t] = start;
  }
  __syncthreads();
  for (int w = wv; w < NC; w += 8) {
    int st = segStart[w * NB + b];
    int cn = segCnt[w * NB + b];
    for (int i = lane; i < cn; i += 64) {
      unsigned e = binned[st + i];
      int p = atomicAdd(&cur[e >> 17], 1);
      csr_src[p] = (int)(e & 0x1FFFFu);   // writes confined to ~33KB bin window
    }
  }
}

// ---- m1[n, f] = bf16((x[n,:] @ W1[:,f]) * dinv[n]) ----
__global__ __launch_bounds__(256) void k_gemm1(const float* __restrict__ x,
                                               const float* __restrict__ W1,
                                               const float* __restrict__ dinv,
                                               __hip_bfloat16* __restrict__ m1) {
  __shared__ float W1s[FIN * FH];  // 32 KB
  for (int i = threadIdx.x; i < FIN * FH; i += 256) W1s[i] = W1[i];
  __syncthreads();
  int lane = threadIdx.x & 63;
  int w = threadIdx.x >> 6;
  for (int grp = blockIdx.x; grp * 4 < N; grp += gridDim.x) {
    int node = grp * 4 + w;
    if (node >= N) continue;
    int nu = __builtin_amdgcn_readfirstlane(node);
    const float* xr = x + (size_t)nu * FIN;
    float a0 = 0.f, a1 = 0.f, a2 = 0.f, a3 = 0.f;
#pragma unroll
    for (int k = 0; k < FIN; k += 4) {
      a0 = fmaf(xr[k + 0], W1s[(k + 0) * FH + lane], a0);
      a1 = fmaf(xr[k + 1], W1s[(k + 1) * FH + lane], a1);
      a2 = fmaf(xr[k + 2], W1s[(k + 2) * FH + lane], a2);
      a3 = fmaf(xr[k + 3], W1s[(k + 3) * FH + lane], a3);
    }
    m1[(size_t)nu * FH + lane] = __float2bfloat16(((a0 + a1) + (a2 + a3)) * dinv[nu]);
  }
}

// ---- conv1: wave-per-node CSR gather (4-deep) + relu + fused @W2 -> m2 ----
__global__ __launch_bounds__(256) void k_agg1(const __hip_bfloat16* __restrict__ m1,
                                              const int* __restrict__ rowptr,
                                              const int* __restrict__ csr_src,
                                              const float* __restrict__ dinv,
                                              const float* __restrict__ b1,
                                              const float* __restrict__ W2,
                                              float* __restrict__ m2) {
  int node = blockIdx.x * 4 + (threadIdx.x >> 6);
  if (node >= N) return;
  int lane = threadIdx.x & 63;
  int nu = __builtin_amdgcn_readfirstlane(node);
  int start = __builtin_amdgcn_readfirstlane(rowptr[nu]);
  int end   = __builtin_amdgcn_readfirstlane(rowptr[nu + 1]);
  float acc = __bfloat162float(m1[(size_t)nu * FH + lane]);  // self-loop
  for (int base = start; base < end; base += 64) {
    int m = min(64, end - base);
    int sv = (lane < m) ? csr_src[base + lane] : 0;  // one coalesced id read
    float a0 = 0.f, a1 = 0.f, a2 = 0.f, a3 = 0.f;
    int j = 0;
    for (; j + 4 <= m; j += 4) {
      int s0 = __shfl(sv, j);
      int s1 = __shfl(sv, j + 1);
      int s2 = __shfl(sv, j + 2);
      int s3 = __shfl(sv, j + 3);
      a0 += __bfloat162float(m1[(size_t)s0 * FH + lane]);
      a1 += __bfloat162float(m1[(size_t)s1 * FH + lane]);
      a2 += __bfloat162float(m1[(size_t)s2 * FH + lane]);
      a3 += __bfloat162float(m1[(size_t)s3 * FH + lane]);
    }
    for (; j < m; ++j)
      a0 += __bfloat162float(m1[(size_t)__shfl(sv, j) * FH + lane]);
    acc += (a0 + a1) + (a2 + a3);
  }
  float dv = dinv[nu];
  float h = fmaxf(fmaf(acc, dv, b1[lane]), 0.f);
  float p0 = h * W2[lane * 2 + 0];
  float p1 = h * W2[lane * 2 + 1];
#pragma unroll
  for (int off = 32; off; off >>= 1) {
    p0 += __shfl_xor(p0, off);
    p1 += __shfl_xor(p1, off);
  }
  if (lane == 0) {
    m2[nu * 2 + 0] = p0 * dv;
    m2[nu * 2 + 1] = p1 * dv;
  }
}

// ---- conv2: wave-per-node light gather + bias + generator mask ----
__global__ __launch_bounds__(256) void k_agg2(const float* __restrict__ m2,
                                              const int* __restrict__ rowptr,
                                              const int* __restrict__ csr_src,
                                              const float* __restrict__ dinv,
                                              const float* __restrict__ b2,
                                              const float* __restrict__ x,
                                              float* __restrict__ out) {
  int node = blockIdx.x * 4 + (threadIdx.x >> 6);
  if (node >= N) return;
  int lane = threadIdx.x & 63;
  int nu = __builtin_amdgcn_readfirstlane(node);
  int start = __builtin_amdgcn_readfirstlane(rowptr[nu]);
  int end   = __builtin_amdgcn_readfirstlane(rowptr[nu + 1]);
  float a0 = 0.f, a1 = 0.f;
  for (int e = start + lane; e < end; e += 64) {
    int s = csr_src[e];
    a0 += m2[s * 2 + 0];
    a1 += m2[s * 2 + 1];
  }
#pragma unroll
  for (int off = 32; off; off >>= 1) {
    a0 += __shfl_xor(a0, off);
    a1 += __shfl_xor(a1, off);
  }
  if (lane == 0) {
    a0 += m2[nu * 2 + 0];  // self-loop
    a1 += m2[nu * 2 + 1];
    float dv = dinv[nu];
    float o0 = a0 * dv + b2[0];
    float o1 = a1 * dv + b2[1];
    float msk = (x[(size_t)nu * FIN] == 1.0f) ? 1.0f : 0.0f;
    out[nu * 2 + 0] = o0 * msk;
    out[nu * 2 + 1] = o1 * msk;
  }
}

extern "C" void kernel_launch(void* const* d_in, const int* in_sizes, int n_in,
                              void* d_out, int out_size, void* d_ws, size_t ws_size,
                              hipStream_t stream) {
  const float* x   = (const float*)d_in[0];
  const int*   ei  = (const int*)d_in[1];  // int32 [2, E] flat
  const float* W1  = (const float*)d_in[2];
  const float* b1  = (const float*)d_in[3];
  const float* W2  = (const float*)d_in[4];
  const float* b2  = (const float*)d_in[5];
  float*       out = (float*)d_out;

  char* w = (char*)d_ws;
  auto alloc = [&](size_t bytes) -> char* {
    char* p = w;
    w += (bytes + 255) & ~(size_t)255;
    return p;
  };
  int*            rowptr   = (int*)alloc((size_t)(N + 1) * 4);
  float*          dinv     = (float*)alloc((size_t)N * 4);
  unsigned*       binned   = (unsigned*)alloc((size_t)E * 4);
  int*            segStart = (int*)alloc((size_t)NC * NB * 4);
  int*            segCnt   = (int*)alloc((size_t)NC * NB * 4);
  int*            binTot   = (int*)alloc((size_t)NB * 4);
  int*            binBase  = (int*)alloc((size_t)(NB + 1) * 4);
  int*            csr_src  = (int*)alloc((size_t)E * 4);
  __hip_bfloat16* m1       = (__hip_bfloat16*)alloc((size_t)N * FH * 2);
  float*          m2       = (float*)alloc((size_t)N * 2 * 4);

  const int* srcA = ei;      // edge_index[0]
  const int* dstA = ei + E;  // edge_index[1]

  k_binA2<<<dim3(NC), dim3(512), 0, stream>>>(srcA, dstA, binned, segStart, segCnt);
  k_binTot<<<dim3(NB), dim3(256), 0, stream>>>(segCnt, binTot);
  k_binScan<<<dim3(1), dim3(64), 0, stream>>>(binTot, binBase, rowptr);
  k_fill3<<<dim3(NB), dim3(512), 0, stream>>>(binned, segStart, segCnt, binBase,
                                              rowptr, dinv, csr_src);
  k_gemm1<<<dim3(1024), dim3(256), 0, stream>>>(x, W1, dinv, m1);
  k_agg1<<<dim3((N + 3) / 4), dim3(256), 0, stream>>>(m1, rowptr, csr_src, dinv, b1, W2, m2);
  k_agg2<<<dim3((N + 3) / 4), dim3(256), 0, stream>>>(m2, rowptr, csr_src, dinv, b2, x, out);
}

// Round 6
// 247.365 us; speedup vs baseline: 6.9107x; 1.3488x over previous
//
#include <hip/hip_runtime.h>
#include <hip/hip_bf16.h>
#include <math.h>

// GCN 2-layer forward on MI355X — v6.
// v5 post-mortem: k_fill3 (118us) read binned data via 195k fragmented ~16-edge
// segments, twice. v6 adds a chunk-offset scan so edges land in CONTIGUOUS
// bin-major windows; the per-bin CSR sort then streams densely.
// Pipeline: cnt -> chunkScan -> binScan -> scat (bin-major binned) ->
//           fill4 (rowptr+dinv+csr from contiguous window) ->
//           gemm1 -> agg1 -> agg2.

constexpr int N   = 100000;
constexpr int E   = 3200000;
constexpr int FIN = 128;
constexpr int FH  = 64;

constexpr int NPB = 256;                      // nodes per bin
constexpr int NB  = (N + NPB - 1) / NPB;      // 391 bins
constexpr int K   = 6400;                     // edges per chunk
constexpr int NC  = E / K;                    // 500 chunks (exact)

// ---- 1: per-(chunk,bin) counts, bin-major layout ----
__global__ __launch_bounds__(512) void k_cnt(const int* __restrict__ dstA,
                                             int* __restrict__ segCnt) {
  __shared__ int bc[NB];
  const int w = blockIdx.x;
  const int base = w * K;
  for (int i = threadIdx.x; i < NB; i += 512) bc[i] = 0;
  __syncthreads();
  for (int i = threadIdx.x; i < K; i += 512)
    atomicAdd(&bc[dstA[base + i] >> 8], 1);
  __syncthreads();
  for (int b = threadIdx.x; b < NB; b += 512) segCnt[b * NC + w] = bc[b];
}

// ---- 2: per-bin exclusive scan over chunks -> lp, binTot ----
__global__ __launch_bounds__(512) void k_chunkScan(const int* __restrict__ segCnt,
                                                   int* __restrict__ lp,
                                                   int* __restrict__ binTot) {
  __shared__ int sh[512];
  const int b = blockIdx.x;
  const int t = threadIdx.x;
  int v = (t < NC) ? segCnt[b * NC + t] : 0;
  sh[t] = v;
  __syncthreads();
  for (int off = 1; off < 512; off <<= 1) {
    int tv = (t >= off) ? sh[t - off] : 0;
    __syncthreads();
    sh[t] += tv;
    __syncthreads();
  }
  if (t < NC) lp[b * NC + t] = sh[t] - v;   // exclusive prefix
  if (t == 511) binTot[b] = sh[511];
}

// ---- 3: tiny serial scan over 391 bins ----
__global__ void k_binScan(const int* __restrict__ binTot,
                          int* __restrict__ binBase, int* __restrict__ rowptr) {
  if (threadIdx.x == 0 && blockIdx.x == 0) {
    int s = 0;
    for (int b = 0; b < NB; ++b) { binBase[b] = s; s += binTot[b]; }
    binBase[NB] = s;
    rowptr[N] = s;  // == E
  }
}

// ---- 4: scatter edges into contiguous bin-major windows ----
__global__ __launch_bounds__(512) void k_scat(const int* __restrict__ srcA,
                                              const int* __restrict__ dstA,
                                              const int* __restrict__ lp,
                                              const int* __restrict__ binBase,
                                              unsigned* __restrict__ binned) {
  __shared__ int lpw[NB];
  __shared__ int cur[NB];
  const int w = blockIdx.x;
  const int base = w * K;
  for (int b = threadIdx.x; b < NB; b += 512) {
    lpw[b] = binBase[b] + lp[b * NC + w];
    cur[b] = 0;
  }
  __syncthreads();
  for (int i = threadIdx.x; i < K; i += 512) {
    int s = srcA[base + i];
    int d = dstA[base + i];
    int b = d >> 8;
    int slot = lpw[b] + atomicAdd(&cur[b], 1);  // WG dirty set ~391 lines: L2-held
    binned[slot] = ((unsigned)(d & 255) << 17) | (unsigned)s;  // src<2^17, dl<2^8
  }
}

// ---- 5: per-bin CSR from contiguous window: count, scan, place ----
__global__ __launch_bounds__(512) void k_fill4(const unsigned* __restrict__ binned,
                                               const int* __restrict__ binBase,
                                               int* __restrict__ rowptr,
                                               float* __restrict__ dinv,
                                               int* __restrict__ csr_src) {
  __shared__ int cnt_s[NPB];
  __shared__ int sh[NPB];
  __shared__ int cur[NPB];
  const int b = blockIdx.x;
  const int t = threadIdx.x;
  const int w0 = binBase[b], w1 = binBase[b + 1];
  if (t < NPB) cnt_s[t] = 0;
  __syncthreads();
  for (int i = w0 + t; i < w1; i += 512)     // dense coalesced stream
    atomicAdd(&cnt_s[binned[i] >> 17], 1);
  __syncthreads();
  int v = 0;
  if (t < NPB) { v = cnt_s[t]; sh[t] = v; }
  __syncthreads();
  for (int off = 1; off < NPB; off <<= 1) {  // Hillis-Steele inclusive
    int tv = (t < NPB && t >= off) ? sh[t - off] : 0;
    __syncthreads();
    if (t < NPB) sh[t] += tv;
    __syncthreads();
  }
  if (t < NPB) {
    int node = b * NPB + t;
    int start = w0 + sh[t] - v;              // exclusive prefix within window
    if (node < N) {
      rowptr[node] = start;
      dinv[node] = 1.0f / sqrtf((float)(v + 1));  // +1 self-loop
    }
    cur[t] = start;
  }
  __syncthreads();
  for (int i = w0 + t; i < w1; i += 512) {   // re-read (L2-hot), place by node
    unsigned e = binned[i];
    int p = atomicAdd(&cur[e >> 17], 1);
    csr_src[p] = (int)(e & 0x1FFFFu);        // scatter confined to ~33KB window
  }
}

// ---- m1[n, f] = bf16((x[n,:] @ W1[:,f]) * dinv[n]) ----
__global__ __launch_bounds__(256) void k_gemm1(const float* __restrict__ x,
                                               const float* __restrict__ W1,
                                               const float* __restrict__ dinv,
                                               __hip_bfloat16* __restrict__ m1) {
  __shared__ float W1s[FIN * FH];  // 32 KB
  for (int i = threadIdx.x; i < FIN * FH; i += 256) W1s[i] = W1[i];
  __syncthreads();
  int lane = threadIdx.x & 63;
  int w = threadIdx.x >> 6;
  for (int grp = blockIdx.x; grp * 4 < N; grp += gridDim.x) {
    int node = grp * 4 + w;
    if (node >= N) continue;
    int nu = __builtin_amdgcn_readfirstlane(node);
    const float* xr = x + (size_t)nu * FIN;
    float a0 = 0.f, a1 = 0.f, a2 = 0.f, a3 = 0.f;
#pragma unroll
    for (int k = 0; k < FIN; k += 4) {
      a0 = fmaf(xr[k + 0], W1s[(k + 0) * FH + lane], a0);
      a1 = fmaf(xr[k + 1], W1s[(k + 1) * FH + lane], a1);
      a2 = fmaf(xr[k + 2], W1s[(k + 2) * FH + lane], a2);
      a3 = fmaf(xr[k + 3], W1s[(k + 3) * FH + lane], a3);
    }
    m1[(size_t)nu * FH + lane] = __float2bfloat16(((a0 + a1) + (a2 + a3)) * dinv[nu]);
  }
}

// ---- conv1: wave-per-node CSR gather (4-deep) + relu + fused @W2 -> m2 ----
__global__ __launch_bounds__(256) void k_agg1(const __hip_bfloat16* __restrict__ m1,
                                              const int* __restrict__ rowptr,
                                              const int* __restrict__ csr_src,
                                              const float* __restrict__ dinv,
                                              const float* __restrict__ b1,
                                              const float* __restrict__ W2,
                                              float* __restrict__ m2) {
  int node = blockIdx.x * 4 + (threadIdx.x >> 6);
  if (node >= N) return;
  int lane = threadIdx.x & 63;
  int nu = __builtin_amdgcn_readfirstlane(node);
  int start = __builtin_amdgcn_readfirstlane(rowptr[nu]);
  int end   = __builtin_amdgcn_readfirstlane(rowptr[nu + 1]);
  float acc = __bfloat162float(m1[(size_t)nu * FH + lane]);  // self-loop
  for (int base = start; base < end; base += 64) {
    int m = min(64, end - base);
    int sv = (lane < m) ? csr_src[base + lane] : 0;  // one coalesced id read
    float a0 = 0.f, a1 = 0.f, a2 = 0.f, a3 = 0.f;
    int j = 0;
    for (; j + 4 <= m; j += 4) {
      int s0 = __shfl(sv, j);
      int s1 = __shfl(sv, j + 1);
      int s2 = __shfl(sv, j + 2);
      int s3 = __shfl(sv, j + 3);
      a0 += __bfloat162float(m1[(size_t)s0 * FH + lane]);
      a1 += __bfloat162float(m1[(size_t)s1 * FH + lane]);
      a2 += __bfloat162float(m1[(size_t)s2 * FH + lane]);
      a3 += __bfloat162float(m1[(size_t)s3 * FH + lane]);
    }
    for (; j < m; ++j)
      a0 += __bfloat162float(m1[(size_t)__shfl(sv, j) * FH + lane]);
    acc += (a0 + a1) + (a2 + a3);
  }
  float dv = dinv[nu];
  float h = fmaxf(fmaf(acc, dv, b1[lane]), 0.f);
  float p0 = h * W2[lane * 2 + 0];
  float p1 = h * W2[lane * 2 + 1];
#pragma unroll
  for (int off = 32; off; off >>= 1) {
    p0 += __shfl_xor(p0, off);
    p1 += __shfl_xor(p1, off);
  }
  if (lane == 0) {
    m2[nu * 2 + 0] = p0 * dv;
    m2[nu * 2 + 1] = p1 * dv;
  }
}

// ---- conv2: wave-per-node light gather + bias + generator mask ----
__global__ __launch_bounds__(256) void k_agg2(const float* __restrict__ m2,
                                              const int* __restrict__ rowptr,
                                              const int* __restrict__ csr_src,
                                              const float* __restrict__ dinv,
                                              const float* __restrict__ b2,
                                              const float* __restrict__ x,
                                              float* __restrict__ out) {
  int node = blockIdx.x * 4 + (threadIdx.x >> 6);
  if (node >= N) return;
  int lane = threadIdx.x & 63;
  int nu = __builtin_amdgcn_readfirstlane(node);
  int start = __builtin_amdgcn_readfirstlane(rowptr[nu]);
  int end   = __builtin_amdgcn_readfirstlane(rowptr[nu + 1]);
  float a0 = 0.f, a1 = 0.f;
  for (int e = start + lane; e < end; e += 64) {
    int s = csr_src[e];
    a0 += m2[s * 2 + 0];
    a1 += m2[s * 2 + 1];
  }
#pragma unroll
  for (int off = 32; off; off >>= 1) {
    a0 += __shfl_xor(a0, off);
    a1 += __shfl_xor(a1, off);
  }
  if (lane == 0) {
    a0 += m2[nu * 2 + 0];  // self-loop
    a1 += m2[nu * 2 + 1];
    float dv = dinv[nu];
    float o0 = a0 * dv + b2[0];
    float o1 = a1 * dv + b2[1];
    float msk = (x[(size_t)nu * FIN] == 1.0f) ? 1.0f : 0.0f;
    out[nu * 2 + 0] = o0 * msk;
    out[nu * 2 + 1] = o1 * msk;
  }
}

extern "C" void kernel_launch(void* const* d_in, const int* in_sizes, int n_in,
                              void* d_out, int out_size, void* d_ws, size_t ws_size,
                              hipStream_t stream) {
  const float* x   = (const float*)d_in[0];
  const int*   ei  = (const int*)d_in[1];  // int32 [2, E] flat
  const float* W1  = (const float*)d_in[2];
  const float* b1  = (const float*)d_in[3];
  const float* W2  = (const float*)d_in[4];
  const float* b2  = (const float*)d_in[5];
  float*       out = (float*)d_out;

  char* w = (char*)d_ws;
  auto alloc = [&](size_t bytes) -> char* {
    char* p = w;
    w += (bytes + 255) & ~(size_t)255;
    return p;
  };
  int*            rowptr  = (int*)alloc((size_t)(N + 1) * 4);
  float*          dinv    = (float*)alloc((size_t)N * 4);
  unsigned*       binned  = (unsigned*)alloc((size_t)E * 4);
  int*            segCnt  = (int*)alloc((size_t)NB * NC * 4);
  int*            lp      = (int*)alloc((size_t)NB * NC * 4);
  int*            binTot  = (int*)alloc((size_t)NB * 4);
  int*            binBase = (int*)alloc((size_t)(NB + 1) * 4);
  int*            csr_src = (int*)alloc((size_t)E * 4);
  __hip_bfloat16* m1      = (__hip_bfloat16*)alloc((size_t)N * FH * 2);
  float*          m2      = (float*)alloc((size_t)N * 2 * 4);

  const int* srcA = ei;      // edge_index[0]
  const int* dstA = ei + E;  // edge_index[1]

  k_cnt<<<dim3(NC), dim3(512), 0, stream>>>(dstA, segCnt);
  k_chunkScan<<<dim3(NB), dim3(512), 0, stream>>>(segCnt, lp, binTot);
  k_binScan<<<dim3(1), dim3(64), 0, stream>>>(binTot, binBase, rowptr);
  k_scat<<<dim3(NC), dim3(512), 0, stream>>>(srcA, dstA, lp, binBase, binned);
  k_fill4<<<dim3(NB), dim3(512), 0, stream>>>(binned, binBase, rowptr, dinv, csr_src);
  k_gemm1<<<dim3(1024), dim3(256), 0, stream>>>(x, W1, dinv, m1);
  k_agg1<<<dim3((N + 3) / 4), dim3(256), 0, stream>>>(m1, rowptr, csr_src, dinv, b1, W2, m2);
  k_agg2<<<dim3((N + 3) / 4), dim3(256), 0, stream>>>(m2, rowptr, csr_src, dinv, b2, x, out);
}

// Round 7
// 211.436 us; speedup vs baseline: 8.0850x; 1.1699x over previous
//
#include <hip/hip_runtime.h>
#include <hip/hip_bf16.h>
#include <math.h>

// GCN 2-layer forward on MI355X — v7.
// v6 post-mortem: k_gemm1 (110us) was LDS-bound: 1 node/wave => re-reads all
// of W1 from LDS per node (3.28 GB LDS traffic, 1:1 FMA:ds_read). v7: 4 nodes
// per wave => one ds_read feeds 4 FMAs (LDS /4), x rows via scalar loads.
// Pipeline: cnt -> chunkScan -> binScan -> scat -> fill4 -> gemm1 -> agg1 -> agg2.

constexpr int N   = 100000;
constexpr int E   = 3200000;
constexpr int FIN = 128;
constexpr int FH  = 64;

constexpr int NPB = 256;                      // nodes per bin
constexpr int NB  = (N + NPB - 1) / NPB;      // 391 bins
constexpr int K   = 6400;                     // edges per chunk
constexpr int NC  = E / K;                    // 500 chunks (exact)

// ---- 1: per-(chunk,bin) counts, bin-major layout ----
__global__ __launch_bounds__(512) void k_cnt(const int* __restrict__ dstA,
                                             int* __restrict__ segCnt) {
  __shared__ int bc[NB];
  const int w = blockIdx.x;
  const int base = w * K;
  for (int i = threadIdx.x; i < NB; i += 512) bc[i] = 0;
  __syncthreads();
  for (int i = threadIdx.x; i < K; i += 512)
    atomicAdd(&bc[dstA[base + i] >> 8], 1);
  __syncthreads();
  for (int b = threadIdx.x; b < NB; b += 512) segCnt[b * NC + w] = bc[b];
}

// ---- 2: per-bin exclusive scan over chunks -> lp, binTot ----
__global__ __launch_bounds__(512) void k_chunkScan(const int* __restrict__ segCnt,
                                                   int* __restrict__ lp,
                                                   int* __restrict__ binTot) {
  __shared__ int sh[512];
  const int b = blockIdx.x;
  const int t = threadIdx.x;
  int v = (t < NC) ? segCnt[b * NC + t] : 0;
  sh[t] = v;
  __syncthreads();
  for (int off = 1; off < 512; off <<= 1) {
    int tv = (t >= off) ? sh[t - off] : 0;
    __syncthreads();
    sh[t] += tv;
    __syncthreads();
  }
  if (t < NC) lp[b * NC + t] = sh[t] - v;   // exclusive prefix
  if (t == 511) binTot[b] = sh[511];
}

// ---- 3: tiny serial scan over 391 bins ----
__global__ void k_binScan(const int* __restrict__ binTot,
                          int* __restrict__ binBase, int* __restrict__ rowptr) {
  if (threadIdx.x == 0 && blockIdx.x == 0) {
    int s = 0;
    for (int b = 0; b < NB; ++b) { binBase[b] = s; s += binTot[b]; }
    binBase[NB] = s;
    rowptr[N] = s;  // == E
  }
}

// ---- 4: scatter edges into contiguous bin-major windows ----
__global__ __launch_bounds__(512) void k_scat(const int* __restrict__ srcA,
                                              const int* __restrict__ dstA,
                                              const int* __restrict__ lp,
                                              const int* __restrict__ binBase,
                                              unsigned* __restrict__ binned) {
  __shared__ int lpw[NB];
  __shared__ int cur[NB];
  const int w = blockIdx.x;
  const int base = w * K;
  for (int b = threadIdx.x; b < NB; b += 512) {
    lpw[b] = binBase[b] + lp[b * NC + w];
    cur[b] = 0;
  }
  __syncthreads();
  for (int i = threadIdx.x; i < K; i += 512) {
    int s = srcA[base + i];
    int d = dstA[base + i];
    int b = d >> 8;
    int slot = lpw[b] + atomicAdd(&cur[b], 1);  // WG dirty set ~391 lines: L2-held
    binned[slot] = ((unsigned)(d & 255) << 17) | (unsigned)s;  // src<2^17, dl<2^8
  }
}

// ---- 5: per-bin CSR from contiguous window: count, scan, place ----
__global__ __launch_bounds__(512) void k_fill4(const unsigned* __restrict__ binned,
                                               const int* __restrict__ binBase,
                                               int* __restrict__ rowptr,
                                               float* __restrict__ dinv,
                                               int* __restrict__ csr_src) {
  __shared__ int cnt_s[NPB];
  __shared__ int sh[NPB];
  __shared__ int cur[NPB];
  const int b = blockIdx.x;
  const int t = threadIdx.x;
  const int w0 = binBase[b], w1 = binBase[b + 1];
  if (t < NPB) cnt_s[t] = 0;
  __syncthreads();
  for (int i = w0 + t; i < w1; i += 512)     // dense coalesced stream
    atomicAdd(&cnt_s[binned[i] >> 17], 1);
  __syncthreads();
  int v = 0;
  if (t < NPB) { v = cnt_s[t]; sh[t] = v; }
  __syncthreads();
  for (int off = 1; off < NPB; off <<= 1) {  // Hillis-Steele inclusive
    int tv = (t < NPB && t >= off) ? sh[t - off] : 0;
    __syncthreads();
    if (t < NPB) sh[t] += tv;
    __syncthreads();
  }
  if (t < NPB) {
    int node = b * NPB + t;
    int start = w0 + sh[t] - v;              // exclusive prefix within window
    if (node < N) {
      rowptr[node] = start;
      dinv[node] = 1.0f / sqrtf((float)(v + 1));  // +1 self-loop
    }
    cur[t] = start;
  }
  __syncthreads();
  for (int i = w0 + t; i < w1; i += 512) {   // re-read (L2-hot), place by node
    unsigned e = binned[i];
    int p = atomicAdd(&cur[e >> 17], 1);
    csr_src[p] = (int)(e & 0x1FFFFu);        // scatter confined to ~33KB window
  }
}

// ---- m1[n, f] = bf16((x[n,:] @ W1[:,f]) * dinv[n]); 4 nodes/wave ----
__global__ __launch_bounds__(256) void k_gemm1(const float* __restrict__ x,
                                               const float* __restrict__ W1,
                                               const float* __restrict__ dinv,
                                               __hip_bfloat16* __restrict__ m1) {
  __shared__ float W1s[FIN * FH];  // 32 KB
  for (int i = threadIdx.x; i < FIN * FH; i += 256) W1s[i] = W1[i];
  __syncthreads();
  const int lane = threadIdx.x & 63;
  const int wv = threadIdx.x >> 6;  // 0..3
  // 4 nodes per wave, 16 per block; N == 6250*16 exactly (no tail).
  const int nb = __builtin_amdgcn_readfirstlane((blockIdx.x * 4 + wv) * 4);
  const float* xr0 = x + (size_t)(nb + 0) * FIN;
  const float* xr1 = x + (size_t)(nb + 1) * FIN;
  const float* xr2 = x + (size_t)(nb + 2) * FIN;
  const float* xr3 = x + (size_t)(nb + 3) * FIN;
  float acc0 = 0.f, acc1 = 0.f, acc2 = 0.f, acc3 = 0.f;
#pragma unroll
  for (int k = 0; k < FIN; k += 4) {
    float w0 = W1s[(k + 0) * FH + lane];
    float w1 = W1s[(k + 1) * FH + lane];
    float w2 = W1s[(k + 2) * FH + lane];
    float w3 = W1s[(k + 3) * FH + lane];
    acc0 = fmaf(xr0[k + 0], w0, acc0); acc1 = fmaf(xr1[k + 0], w0, acc1);
    acc2 = fmaf(xr2[k + 0], w0, acc2); acc3 = fmaf(xr3[k + 0], w0, acc3);
    acc0 = fmaf(xr0[k + 1], w1, acc0); acc1 = fmaf(xr1[k + 1], w1, acc1);
    acc2 = fmaf(xr2[k + 1], w1, acc2); acc3 = fmaf(xr3[k + 1], w1, acc3);
    acc0 = fmaf(xr0[k + 2], w2, acc0); acc1 = fmaf(xr1[k + 2], w2, acc1);
    acc2 = fmaf(xr2[k + 2], w2, acc2); acc3 = fmaf(xr3[k + 2], w2, acc3);
    acc0 = fmaf(xr0[k + 3], w3, acc0); acc1 = fmaf(xr1[k + 3], w3, acc1);
    acc2 = fmaf(xr2[k + 3], w3, acc2); acc3 = fmaf(xr3[k + 3], w3, acc3);
  }
  m1[(size_t)(nb + 0) * FH + lane] = __float2bfloat16(acc0 * dinv[nb + 0]);
  m1[(size_t)(nb + 1) * FH + lane] = __float2bfloat16(acc1 * dinv[nb + 1]);
  m1[(size_t)(nb + 2) * FH + lane] = __float2bfloat16(acc2 * dinv[nb + 2]);
  m1[(size_t)(nb + 3) * FH + lane] = __float2bfloat16(acc3 * dinv[nb + 3]);
}

// ---- conv1: wave-per-node CSR gather (4-deep) + relu + fused @W2 -> m2 ----
__global__ __launch_bounds__(256) void k_agg1(const __hip_bfloat16* __restrict__ m1,
                                              const int* __restrict__ rowptr,
                                              const int* __restrict__ csr_src,
                                              const float* __restrict__ dinv,
                                              const float* __restrict__ b1,
                                              const float* __restrict__ W2,
                                              float* __restrict__ m2) {
  int node = blockIdx.x * 4 + (threadIdx.x >> 6);
  if (node >= N) return;
  int lane = threadIdx.x & 63;
  int nu = __builtin_amdgcn_readfirstlane(node);
  int start = __builtin_amdgcn_readfirstlane(rowptr[nu]);
  int end   = __builtin_amdgcn_readfirstlane(rowptr[nu + 1]);
  float acc = __bfloat162float(m1[(size_t)nu * FH + lane]);  // self-loop
  for (int base = start; base < end; base += 64) {
    int m = min(64, end - base);
    int sv = (lane < m) ? csr_src[base + lane] : 0;  // one coalesced id read
    float a0 = 0.f, a1 = 0.f, a2 = 0.f, a3 = 0.f;
    int j = 0;
    for (; j + 4 <= m; j += 4) {
      int s0 = __shfl(sv, j);
      int s1 = __shfl(sv, j + 1);
      int s2 = __shfl(sv, j + 2);
      int s3 = __shfl(sv, j + 3);
      a0 += __bfloat162float(m1[(size_t)s0 * FH + lane]);
      a1 += __bfloat162float(m1[(size_t)s1 * FH + lane]);
      a2 += __bfloat162float(m1[(size_t)s2 * FH + lane]);
      a3 += __bfloat162float(m1[(size_t)s3 * FH + lane]);
    }
    for (; j < m; ++j)
      a0 += __bfloat162float(m1[(size_t)__shfl(sv, j) * FH + lane]);
    acc += (a0 + a1) + (a2 + a3);
  }
  float dv = dinv[nu];
  float h = fmaxf(fmaf(acc, dv, b1[lane]), 0.f);
  float p0 = h * W2[lane * 2 + 0];
  float p1 = h * W2[lane * 2 + 1];
#pragma unroll
  for (int off = 32; off; off >>= 1) {
    p0 += __shfl_xor(p0, off);
    p1 += __shfl_xor(p1, off);
  }
  if (lane == 0) {
    m2[nu * 2 + 0] = p0 * dv;
    m2[nu * 2 + 1] = p1 * dv;
  }
}

// ---- conv2: wave-per-node light gather + bias + generator mask ----
__global__ __launch_bounds__(256) void k_agg2(const float* __restrict__ m2,
                                              const int* __restrict__ rowptr,
                                              const int* __restrict__ csr_src,
                                              const float* __restrict__ dinv,
                                              const float* __restrict__ b2,
                                              const float* __restrict__ x,
                                              float* __restrict__ out) {
  int node = blockIdx.x * 4 + (threadIdx.x >> 6);
  if (node >= N) return;
  int lane = threadIdx.x & 63;
  int nu = __builtin_amdgcn_readfirstlane(node);
  int start = __builtin_amdgcn_readfirstlane(rowptr[nu]);
  int end   = __builtin_amdgcn_readfirstlane(rowptr[nu + 1]);
  float a0 = 0.f, a1 = 0.f;
  for (int e = start + lane; e < end; e += 64) {
    int s = csr_src[e];
    a0 += m2[s * 2 + 0];
    a1 += m2[s * 2 + 1];
  }
#pragma unroll
  for (int off = 32; off; off >>= 1) {
    a0 += __shfl_xor(a0, off);
    a1 += __shfl_xor(a1, off);
  }
  if (lane == 0) {
    a0 += m2[nu * 2 + 0];  // self-loop
    a1 += m2[nu * 2 + 1];
    float dv = dinv[nu];
    float o0 = a0 * dv + b2[0];
    float o1 = a1 * dv + b2[1];
    float msk = (x[(size_t)nu * FIN] == 1.0f) ? 1.0f : 0.0f;
    out[nu * 2 + 0] = o0 * msk;
    out[nu * 2 + 1] = o1 * msk;
  }
}

extern "C" void kernel_launch(void* const* d_in, const int* in_sizes, int n_in,
                              void* d_out, int out_size, void* d_ws, size_t ws_size,
                              hipStream_t stream) {
  const float* x   = (const float*)d_in[0];
  const int*   ei  = (const int*)d_in[1];  // int32 [2, E] flat
  const float* W1  = (const float*)d_in[2];
  const float* b1  = (const float*)d_in[3];
  const float* W2  = (const float*)d_in[4];
  const float* b2  = (const float*)d_in[5];
  float*       out = (float*)d_out;

  char* w = (char*)d_ws;
  auto alloc = [&](size_t bytes) -> char* {
    char* p = w;
    w += (bytes + 255) & ~(size_t)255;
    return p;
  };
  int*            rowptr  = (int*)alloc((size_t)(N + 1) * 4);
  float*          dinv    = (float*)alloc((size_t)N * 4);
  unsigned*       binned  = (unsigned*)alloc((size_t)E * 4);
  int*            segCnt  = (int*)alloc((size_t)NB * NC * 4);
  int*            lp      = (int*)alloc((size_t)NB * NC * 4);
  int*            binTot  = (int*)alloc((size_t)NB * 4);
  int*            binBase = (int*)alloc((size_t)(NB + 1) * 4);
  int*            csr_src = (int*)alloc((size_t)E * 4);
  __hip_bfloat16* m1      = (__hip_bfloat16*)alloc((size_t)N * FH * 2);
  float*          m2      = (float*)alloc((size_t)N * 2 * 4);

  const int* srcA = ei;      // edge_index[0]
  const int* dstA = ei + E;  // edge_index[1]

  k_cnt<<<dim3(NC), dim3(512), 0, stream>>>(dstA, segCnt);
  k_chunkScan<<<dim3(NB), dim3(512), 0, stream>>>(segCnt, lp, binTot);
  k_binScan<<<dim3(1), dim3(64), 0, stream>>>(binTot, binBase, rowptr);
  k_scat<<<dim3(NC), dim3(512), 0, stream>>>(srcA, dstA, lp, binBase, binned);
  k_fill4<<<dim3(NB), dim3(512), 0, stream>>>(binned, binBase, rowptr, dinv, csr_src);
  k_gemm1<<<dim3(N / 16), dim3(256), 0, stream>>>(x, W1, dinv, m1);  // 6250 blocks
  k_agg1<<<dim3((N + 3) / 4), dim3(256), 0, stream>>>(m1, rowptr, csr_src, dinv, b1, W2, m2);
  k_agg2<<<dim3((N + 3) / 4), dim3(256), 0, stream>>>(m2, rowptr, csr_src, dinv, b2, x, out);
}

// Round 8
// 205.704 us; speedup vs baseline: 8.3104x; 1.0279x over previous
//
#include <hip/hip_runtime.h>
#include <hip/hip_bf16.h>
#include <math.h>

// GCN 2-layer forward on MI355X — v8.
// v7 post-mortem: k_agg1 (80us) is instruction-issue-bound (~8 wave-insts per
// edge: shfl+ushort load+cvt+add). v8: 2 edges per dword load — lanes 0-31 =
// edge j (32 bf16x2 feature-pairs), lanes 32-63 = edge j+1; unpack via shifts.
// Pipeline: cnt -> chunkScan -> binScan -> scat -> fill4 -> gemm1 -> agg1 -> agg2.

constexpr int N   = 100000;
constexpr int E   = 3200000;
constexpr int FIN = 128;
constexpr int FH  = 64;

constexpr int NPB = 256;                      // nodes per bin
constexpr int NB  = (N + NPB - 1) / NPB;      // 391 bins
constexpr int K   = 6400;                     // edges per chunk
constexpr int NC  = E / K;                    // 500 chunks (exact)

// ---- 1: per-(chunk,bin) counts, bin-major layout ----
__global__ __launch_bounds__(512) void k_cnt(const int* __restrict__ dstA,
                                             int* __restrict__ segCnt) {
  __shared__ int bc[NB];
  const int w = blockIdx.x;
  const int base = w * K;
  for (int i = threadIdx.x; i < NB; i += 512) bc[i] = 0;
  __syncthreads();
  for (int i = threadIdx.x; i < K; i += 512)
    atomicAdd(&bc[dstA[base + i] >> 8], 1);
  __syncthreads();
  for (int b = threadIdx.x; b < NB; b += 512) segCnt[b * NC + w] = bc[b];
}

// ---- 2: per-bin exclusive scan over chunks -> lp, binTot ----
__global__ __launch_bounds__(512) void k_chunkScan(const int* __restrict__ segCnt,
                                                   int* __restrict__ lp,
                                                   int* __restrict__ binTot) {
  __shared__ int sh[512];
  const int b = blockIdx.x;
  const int t = threadIdx.x;
  int v = (t < NC) ? segCnt[b * NC + t] : 0;
  sh[t] = v;
  __syncthreads();
  for (int off = 1; off < 512; off <<= 1) {
    int tv = (t >= off) ? sh[t - off] : 0;
    __syncthreads();
    sh[t] += tv;
    __syncthreads();
  }
  if (t < NC) lp[b * NC + t] = sh[t] - v;   // exclusive prefix
  if (t == 511) binTot[b] = sh[511];
}

// ---- 3: tiny serial scan over 391 bins ----
__global__ void k_binScan(const int* __restrict__ binTot,
                          int* __restrict__ binBase, int* __restrict__ rowptr) {
  if (threadIdx.x == 0 && blockIdx.x == 0) {
    int s = 0;
    for (int b = 0; b < NB; ++b) { binBase[b] = s; s += binTot[b]; }
    binBase[NB] = s;
    rowptr[N] = s;  // == E
  }
}

// ---- 4: scatter edges into contiguous bin-major windows ----
__global__ __launch_bounds__(512) void k_scat(const int* __restrict__ srcA,
                                              const int* __restrict__ dstA,
                                              const int* __restrict__ lp,
                                              const int* __restrict__ binBase,
                                              unsigned* __restrict__ binned) {
  __shared__ int lpw[NB];
  __shared__ int cur[NB];
  const int w = blockIdx.x;
  const int base = w * K;
  for (int b = threadIdx.x; b < NB; b += 512) {
    lpw[b] = binBase[b] + lp[b * NC + w];
    cur[b] = 0;
  }
  __syncthreads();
  for (int i = threadIdx.x; i < K; i += 512) {
    int s = srcA[base + i];
    int d = dstA[base + i];
    int b = d >> 8;
    int slot = lpw[b] + atomicAdd(&cur[b], 1);  // WG dirty set ~391 lines: L2-held
    binned[slot] = ((unsigned)(d & 255) << 17) | (unsigned)s;  // src<2^17, dl<2^8
  }
}

// ---- 5: per-bin CSR from contiguous window: count, scan, place ----
__global__ __launch_bounds__(512) void k_fill4(const unsigned* __restrict__ binned,
                                               const int* __restrict__ binBase,
                                               int* __restrict__ rowptr,
                                               float* __restrict__ dinv,
                                               int* __restrict__ csr_src) {
  __shared__ int cnt_s[NPB];
  __shared__ int sh[NPB];
  __shared__ int cur[NPB];
  const int b = blockIdx.x;
  const int t = threadIdx.x;
  const int w0 = binBase[b], w1 = binBase[b + 1];
  if (t < NPB) cnt_s[t] = 0;
  __syncthreads();
  for (int i = w0 + t; i < w1; i += 512)     // dense coalesced stream
    atomicAdd(&cnt_s[binned[i] >> 17], 1);
  __syncthreads();
  int v = 0;
  if (t < NPB) { v = cnt_s[t]; sh[t] = v; }
  __syncthreads();
  for (int off = 1; off < NPB; off <<= 1) {  // Hillis-Steele inclusive
    int tv = (t < NPB && t >= off) ? sh[t - off] : 0;
    __syncthreads();
    if (t < NPB) sh[t] += tv;
    __syncthreads();
  }
  if (t < NPB) {
    int node = b * NPB + t;
    int start = w0 + sh[t] - v;              // exclusive prefix within window
    if (node < N) {
      rowptr[node] = start;
      dinv[node] = 1.0f / sqrtf((float)(v + 1));  // +1 self-loop
    }
    cur[t] = start;
  }
  __syncthreads();
  for (int i = w0 + t; i < w1; i += 512) {   // re-read (L2-hot), place by node
    unsigned e = binned[i];
    int p = atomicAdd(&cur[e >> 17], 1);
    csr_src[p] = (int)(e & 0x1FFFFu);        // scatter confined to ~33KB window
  }
}

// ---- m1[n, f] = bf16((x[n,:] @ W1[:,f]) * dinv[n]); 4 nodes/wave ----
__global__ __launch_bounds__(256) void k_gemm1(const float* __restrict__ x,
                                               const float* __restrict__ W1,
                                               const float* __restrict__ dinv,
                                               __hip_bfloat16* __restrict__ m1) {
  __shared__ float W1s[FIN * FH];  // 32 KB
  for (int i = threadIdx.x; i < FIN * FH; i += 256) W1s[i] = W1[i];
  __syncthreads();
  const int lane = threadIdx.x & 63;
  const int wv = threadIdx.x >> 6;  // 0..3
  // 4 nodes per wave, 16 per block; N == 6250*16 exactly (no tail).
  const int nb = __builtin_amdgcn_readfirstlane((blockIdx.x * 4 + wv) * 4);
  const float* xr0 = x + (size_t)(nb + 0) * FIN;
  const float* xr1 = x + (size_t)(nb + 1) * FIN;
  const float* xr2 = x + (size_t)(nb + 2) * FIN;
  const float* xr3 = x + (size_t)(nb + 3) * FIN;
  float acc0 = 0.f, acc1 = 0.f, acc2 = 0.f, acc3 = 0.f;
#pragma unroll
  for (int k = 0; k < FIN; k += 4) {
    float w0 = W1s[(k + 0) * FH + lane];
    float w1 = W1s[(k + 1) * FH + lane];
    float w2 = W1s[(k + 2) * FH + lane];
    float w3 = W1s[(k + 3) * FH + lane];
    acc0 = fmaf(xr0[k + 0], w0, acc0); acc1 = fmaf(xr1[k + 0], w0, acc1);
    acc2 = fmaf(xr2[k + 0], w0, acc2); acc3 = fmaf(xr3[k + 0], w0, acc3);
    acc0 = fmaf(xr0[k + 1], w1, acc0); acc1 = fmaf(xr1[k + 1], w1, acc1);
    acc2 = fmaf(xr2[k + 1], w1, acc2); acc3 = fmaf(xr3[k + 1], w1, acc3);
    acc0 = fmaf(xr0[k + 2], w2, acc0); acc1 = fmaf(xr1[k + 2], w2, acc1);
    acc2 = fmaf(xr2[k + 2], w2, acc2); acc3 = fmaf(xr3[k + 2], w2, acc3);
    acc0 = fmaf(xr0[k + 3], w3, acc0); acc1 = fmaf(xr1[k + 3], w3, acc1);
    acc2 = fmaf(xr2[k + 3], w3, acc2); acc3 = fmaf(xr3[k + 3], w3, acc3);
  }
  m1[(size_t)(nb + 0) * FH + lane] = __float2bfloat16(acc0 * dinv[nb + 0]);
  m1[(size_t)(nb + 1) * FH + lane] = __float2bfloat16(acc1 * dinv[nb + 1]);
  m1[(size_t)(nb + 2) * FH + lane] = __float2bfloat16(acc2 * dinv[nb + 2]);
  m1[(size_t)(nb + 3) * FH + lane] = __float2bfloat16(acc3 * dinv[nb + 3]);
}

// ---- conv1: wave-per-node, 2 edges per dword load + relu + fused @W2 ----
__global__ __launch_bounds__(256) void k_agg1(const __hip_bfloat16* __restrict__ m1,
                                              const int* __restrict__ rowptr,
                                              const int* __restrict__ csr_src,
                                              const float* __restrict__ dinv,
                                              const float* __restrict__ b1,
                                              const float* __restrict__ W2,
                                              float* __restrict__ m2) {
  int node = blockIdx.x * 4 + (threadIdx.x >> 6);
  if (node >= N) return;
  const int lane = threadIdx.x & 63;
  const int nu = __builtin_amdgcn_readfirstlane(node);
  const int start = __builtin_amdgcn_readfirstlane(rowptr[nu]);
  const int end   = __builtin_amdgcn_readfirstlane(rowptr[nu + 1]);
  const unsigned* __restrict__ m1d = (const unsigned*)m1;  // row = 32 dwords
  const int half = lane >> 5;      // 0: edge j, 1: edge j+1
  const int fp   = lane & 31;      // feature pair -> features 2fp, 2fp+1
  float a0 = 0.f, a1 = 0.f, c0 = 0.f, c1 = 0.f;
  for (int base = start; base < end; base += 64) {
    int m = min(64, end - base);
    int sv = (lane < m) ? csr_src[base + lane] : 0;  // coalesced id read
    int mE = m & ~1;
    int j = 0;
    for (; j + 4 <= mE; j += 4) {      // 2 loads in flight
      int sA = __shfl(sv, j + half);
      int sB = __shfl(sv, j + 2 + half);
      unsigned vA = m1d[(size_t)sA * 32 + fp];
      unsigned vB = m1d[(size_t)sB * 32 + fp];
      a0 += __uint_as_float(vA << 16);
      a1 += __uint_as_float(vA & 0xffff0000u);
      c0 += __uint_as_float(vB << 16);
      c1 += __uint_as_float(vB & 0xffff0000u);
    }
    for (; j < mE; j += 2) {
      int s = __shfl(sv, j + half);
      unsigned v = m1d[(size_t)s * 32 + fp];
      a0 += __uint_as_float(v << 16);
      a1 += __uint_as_float(v & 0xffff0000u);
    }
    if (mE < m) {                       // odd leftover: half 0 only
      int s = __shfl(sv, mE);
      if (half == 0) {
        unsigned v = m1d[(size_t)s * 32 + fp];
        a0 += __uint_as_float(v << 16);
        a1 += __uint_as_float(v & 0xffff0000u);
      }
    }
  }
  a0 += c0; a1 += c1;
  a0 += __shfl_xor(a0, 32);            // combine edge-halves
  a1 += __shfl_xor(a1, 32);
  {                                     // self-loop (post-combine: uniform)
    unsigned v = m1d[(size_t)nu * 32 + fp];
    a0 += __uint_as_float(v << 16);
    a1 += __uint_as_float(v & 0xffff0000u);
  }
  const float dv = dinv[nu];
  const float2 bv  = ((const float2*)b1)[fp];
  const float2 w2a = ((const float2*)W2)[fp * 2];      // row f0 of W2[64][2]
  const float2 w2b = ((const float2*)W2)[fp * 2 + 1];  // row f1
  float h0 = fmaxf(fmaf(a0, dv, bv.x), 0.f);
  float h1 = fmaxf(fmaf(a1, dv, bv.y), 0.f);
  float p0 = h0 * w2a.x + h1 * w2b.x;
  float p1 = h0 * w2a.y + h1 * w2b.y;
#pragma unroll
  for (int off = 16; off; off >>= 1) {  // reduce over 32 feature-pair lanes
    p0 += __shfl_xor(p0, off);
    p1 += __shfl_xor(p1, off);
  }
  if (lane == 0) {
    m2[nu * 2 + 0] = p0 * dv;
    m2[nu * 2 + 1] = p1 * dv;
  }
}

// ---- conv2: wave-per-node light gather + bias + generator mask ----
__global__ __launch_bounds__(256) void k_agg2(const float* __restrict__ m2,
                                              const int* __restrict__ rowptr,
                                              const int* __restrict__ csr_src,
                                              const float* __restrict__ dinv,
                                              const float* __restrict__ b2,
                                              const float* __restrict__ x,
                                              float* __restrict__ out) {
  int node = blockIdx.x * 4 + (threadIdx.x >> 6);
  if (node >= N) return;
  int lane = threadIdx.x & 63;
  int nu = __builtin_amdgcn_readfirstlane(node);
  int start = __builtin_amdgcn_readfirstlane(rowptr[nu]);
  int end   = __builtin_amdgcn_readfirstlane(rowptr[nu + 1]);
  float a0 = 0.f, a1 = 0.f;
  for (int e = start + lane; e < end; e += 64) {
    int s = csr_src[e];
    a0 += m2[s * 2 + 0];
    a1 += m2[s * 2 + 1];
  }
#pragma unroll
  for (int off = 32; off; off >>= 1) {
    a0 += __shfl_xor(a0, off);
    a1 += __shfl_xor(a1, off);
  }
  if (lane == 0) {
    a0 += m2[nu * 2 + 0];  // self-loop
    a1 += m2[nu * 2 + 1];
    float dv = dinv[nu];
    float o0 = a0 * dv + b2[0];
    float o1 = a1 * dv + b2[1];
    float msk = (x[(size_t)nu * FIN] == 1.0f) ? 1.0f : 0.0f;
    out[nu * 2 + 0] = o0 * msk;
    out[nu * 2 + 1] = o1 * msk;
  }
}

extern "C" void kernel_launch(void* const* d_in, const int* in_sizes, int n_in,
                              void* d_out, int out_size, void* d_ws, size_t ws_size,
                              hipStream_t stream) {
  const float* x   = (const float*)d_in[0];
  const int*   ei  = (const int*)d_in[1];  // int32 [2, E] flat
  const float* W1  = (const float*)d_in[2];
  const float* b1  = (const float*)d_in[3];
  const float* W2  = (const float*)d_in[4];
  const float* b2  = (const float*)d_in[5];
  float*       out = (float*)d_out;

  char* w = (char*)d_ws;
  auto alloc = [&](size_t bytes) -> char* {
    char* p = w;
    w += (bytes + 255) & ~(size_t)255;
    return p;
  };
  int*            rowptr  = (int*)alloc((size_t)(N + 1) * 4);
  float*          dinv    = (float*)alloc((size_t)N * 4);
  unsigned*       binned  = (unsigned*)alloc((size_t)E * 4);
  int*            segCnt  = (int*)alloc((size_t)NB * NC * 4);
  int*            lp      = (int*)alloc((size_t)NB * NC * 4);
  int*            binTot  = (int*)alloc((size_t)NB * 4);
  int*            binBase = (int*)alloc((size_t)(NB + 1) * 4);
  int*            csr_src = (int*)alloc((size_t)E * 4);
  __hip_bfloat16* m1      = (__hip_bfloat16*)alloc((size_t)N * FH * 2);
  float*          m2      = (float*)alloc((size_t)N * 2 * 4);

  const int* srcA = ei;      // edge_index[0]
  const int* dstA = ei + E;  // edge_index[1]

  k_cnt<<<dim3(NC), dim3(512), 0, stream>>>(dstA, segCnt);
  k_chunkScan<<<dim3(NB), dim3(512), 0, stream>>>(segCnt, lp, binTot);
  k_binScan<<<dim3(1), dim3(64), 0, stream>>>(binTot, binBase, rowptr);
  k_scat<<<dim3(NC), dim3(512), 0, stream>>>(srcA, dstA, lp, binBase, binned);
  k_fill4<<<dim3(NB), dim3(512), 0, stream>>>(binned, binBase, rowptr, dinv, csr_src);
  k_gemm1<<<dim3(N / 16), dim3(256), 0, stream>>>(x, W1, dinv, m1);  // 6250 blocks
  k_agg1<<<dim3((N + 3) / 4), dim3(256), 0, stream>>>(m1, rowptr, csr_src, dinv, b1, W2, m2);
  k_agg2<<<dim3((N + 3) / 4), dim3(256), 0, stream>>>(m2, rowptr, csr_src, dinv, b2, x, out);
}

// Round 9
// 197.086 us; speedup vs baseline: 8.6737x; 1.0437x over previous
//
#include <hip/hip_runtime.h>
#include <hip/hip_bf16.h>
#include <math.h>

// GCN 2-layer forward on MI355X — v9.
// v8 post-mortem: agg1 still issue+latency bound (~13 wave-insts/edge at 45%
// VALUBusy; 1 narrow load per 2 edges). v9: 8 edges per wave-load — lane
// group g=lane>>3 owns edge j+g, q=lane&7 loads uint4 (8 bf16 features) of
// that row; one global_load_dwordx4 moves 8 full 128B rows.
// Pipeline: cnt -> chunkScan -> binScan -> scat -> fill4 -> gemm1 -> agg1 -> agg2.

constexpr int N   = 100000;
constexpr int E   = 3200000;
constexpr int FIN = 128;
constexpr int FH  = 64;

constexpr int NPB = 256;                      // nodes per bin
constexpr int NB  = (N + NPB - 1) / NPB;      // 391 bins
constexpr int K   = 6400;                     // edges per chunk
constexpr int NC  = E / K;                    // 500 chunks (exact)

// ---- 1: per-(chunk,bin) counts, bin-major layout ----
__global__ __launch_bounds__(512) void k_cnt(const int* __restrict__ dstA,
                                             int* __restrict__ segCnt) {
  __shared__ int bc[NB];
  const int w = blockIdx.x;
  const int base = w * K;
  for (int i = threadIdx.x; i < NB; i += 512) bc[i] = 0;
  __syncthreads();
  for (int i = threadIdx.x; i < K; i += 512)
    atomicAdd(&bc[dstA[base + i] >> 8], 1);
  __syncthreads();
  for (int b = threadIdx.x; b < NB; b += 512) segCnt[b * NC + w] = bc[b];
}

// ---- 2: per-bin exclusive scan over chunks -> lp, binTot ----
__global__ __launch_bounds__(512) void k_chunkScan(const int* __restrict__ segCnt,
                                                   int* __restrict__ lp,
                                                   int* __restrict__ binTot) {
  __shared__ int sh[512];
  const int b = blockIdx.x;
  const int t = threadIdx.x;
  int v = (t < NC) ? segCnt[b * NC + t] : 0;
  sh[t] = v;
  __syncthreads();
  for (int off = 1; off < 512; off <<= 1) {
    int tv = (t >= off) ? sh[t - off] : 0;
    __syncthreads();
    sh[t] += tv;
    __syncthreads();
  }
  if (t < NC) lp[b * NC + t] = sh[t] - v;   // exclusive prefix
  if (t == 511) binTot[b] = sh[511];
}

// ---- 3: tiny serial scan over 391 bins ----
__global__ void k_binScan(const int* __restrict__ binTot,
                          int* __restrict__ binBase, int* __restrict__ rowptr) {
  if (threadIdx.x == 0 && blockIdx.x == 0) {
    int s = 0;
    for (int b = 0; b < NB; ++b) { binBase[b] = s; s += binTot[b]; }
    binBase[NB] = s;
    rowptr[N] = s;  // == E
  }
}

// ---- 4: scatter edges into contiguous bin-major windows ----
__global__ __launch_bounds__(512) void k_scat(const int* __restrict__ srcA,
                                              const int* __restrict__ dstA,
                                              const int* __restrict__ lp,
                                              const int* __restrict__ binBase,
                                              unsigned* __restrict__ binned) {
  __shared__ int lpw[NB];
  __shared__ int cur[NB];
  const int w = blockIdx.x;
  const int base = w * K;
  for (int b = threadIdx.x; b < NB; b += 512) {
    lpw[b] = binBase[b] + lp[b * NC + w];
    cur[b] = 0;
  }
  __syncthreads();
  for (int i = threadIdx.x; i < K; i += 512) {
    int s = srcA[base + i];
    int d = dstA[base + i];
    int b = d >> 8;
    int slot = lpw[b] + atomicAdd(&cur[b], 1);  // WG dirty set ~391 lines: L2-held
    binned[slot] = ((unsigned)(d & 255) << 17) | (unsigned)s;  // src<2^17, dl<2^8
  }
}

// ---- 5: per-bin CSR from contiguous window: count, scan, place ----
__global__ __launch_bounds__(512) void k_fill4(const unsigned* __restrict__ binned,
                                               const int* __restrict__ binBase,
                                               int* __restrict__ rowptr,
                                               float* __restrict__ dinv,
                                               int* __restrict__ csr_src) {
  __shared__ int cnt_s[NPB];
  __shared__ int sh[NPB];
  __shared__ int cur[NPB];
  const int b = blockIdx.x;
  const int t = threadIdx.x;
  const int w0 = binBase[b], w1 = binBase[b + 1];
  if (t < NPB) cnt_s[t] = 0;
  __syncthreads();
  for (int i = w0 + t; i < w1; i += 512)     // dense coalesced stream
    atomicAdd(&cnt_s[binned[i] >> 17], 1);
  __syncthreads();
  int v = 0;
  if (t < NPB) { v = cnt_s[t]; sh[t] = v; }
  __syncthreads();
  for (int off = 1; off < NPB; off <<= 1) {  // Hillis-Steele inclusive
    int tv = (t < NPB && t >= off) ? sh[t - off] : 0;
    __syncthreads();
    if (t < NPB) sh[t] += tv;
    __syncthreads();
  }
  if (t < NPB) {
    int node = b * NPB + t;
    int start = w0 + sh[t] - v;              // exclusive prefix within window
    if (node < N) {
      rowptr[node] = start;
      dinv[node] = 1.0f / sqrtf((float)(v + 1));  // +1 self-loop
    }
    cur[t] = start;
  }
  __syncthreads();
  for (int i = w0 + t; i < w1; i += 512) {   // re-read (L2-hot), place by node
    unsigned e = binned[i];
    int p = atomicAdd(&cur[e >> 17], 1);
    csr_src[p] = (int)(e & 0x1FFFFu);        // scatter confined to ~33KB window
  }
}

// ---- m1[n, f] = bf16((x[n,:] @ W1[:,f]) * dinv[n]); 4 nodes/wave ----
__global__ __launch_bounds__(256) void k_gemm1(const float* __restrict__ x,
                                               const float* __restrict__ W1,
                                               const float* __restrict__ dinv,
                                               __hip_bfloat16* __restrict__ m1) {
  __shared__ float W1s[FIN * FH];  // 32 KB
  for (int i = threadIdx.x; i < FIN * FH; i += 256) W1s[i] = W1[i];
  __syncthreads();
  const int lane = threadIdx.x & 63;
  const int wv = threadIdx.x >> 6;  // 0..3
  // 4 nodes per wave, 16 per block; N == 6250*16 exactly (no tail).
  const int nb = __builtin_amdgcn_readfirstlane((blockIdx.x * 4 + wv) * 4);
  const float* xr0 = x + (size_t)(nb + 0) * FIN;
  const float* xr1 = x + (size_t)(nb + 1) * FIN;
  const float* xr2 = x + (size_t)(nb + 2) * FIN;
  const float* xr3 = x + (size_t)(nb + 3) * FIN;
  float acc0 = 0.f, acc1 = 0.f, acc2 = 0.f, acc3 = 0.f;
#pragma unroll
  for (int k = 0; k < FIN; k += 4) {
    float w0 = W1s[(k + 0) * FH + lane];
    float w1 = W1s[(k + 1) * FH + lane];
    float w2 = W1s[(k + 2) * FH + lane];
    float w3 = W1s[(k + 3) * FH + lane];
    acc0 = fmaf(xr0[k + 0], w0, acc0); acc1 = fmaf(xr1[k + 0], w0, acc1);
    acc2 = fmaf(xr2[k + 0], w0, acc2); acc3 = fmaf(xr3[k + 0], w0, acc3);
    acc0 = fmaf(xr0[k + 1], w1, acc0); acc1 = fmaf(xr1[k + 1], w1, acc1);
    acc2 = fmaf(xr2[k + 1], w1, acc2); acc3 = fmaf(xr3[k + 1], w1, acc3);
    acc0 = fmaf(xr0[k + 2], w2, acc0); acc1 = fmaf(xr1[k + 2], w2, acc1);
    acc2 = fmaf(xr2[k + 2], w2, acc2); acc3 = fmaf(xr3[k + 2], w2, acc3);
    acc0 = fmaf(xr0[k + 3], w3, acc0); acc1 = fmaf(xr1[k + 3], w3, acc1);
    acc2 = fmaf(xr2[k + 3], w3, acc2); acc3 = fmaf(xr3[k + 3], w3, acc3);
  }
  m1[(size_t)(nb + 0) * FH + lane] = __float2bfloat16(acc0 * dinv[nb + 0]);
  m1[(size_t)(nb + 1) * FH + lane] = __float2bfloat16(acc1 * dinv[nb + 1]);
  m1[(size_t)(nb + 2) * FH + lane] = __float2bfloat16(acc2 * dinv[nb + 2]);
  m1[(size_t)(nb + 3) * FH + lane] = __float2bfloat16(acc3 * dinv[nb + 3]);
}

// ---- conv1: wave-per-node, 8 edges per wave-load (uint4 = 8 bf16/lane) ----
__global__ __launch_bounds__(256) void k_agg1(const __hip_bfloat16* __restrict__ m1,
                                              const int* __restrict__ rowptr,
                                              const int* __restrict__ csr_src,
                                              const float* __restrict__ dinv,
                                              const float* __restrict__ b1,
                                              const float* __restrict__ W2,
                                              float* __restrict__ m2) {
  int node = blockIdx.x * 4 + (threadIdx.x >> 6);
  if (node >= N) return;
  const int lane = threadIdx.x & 63;
  const int nu = __builtin_amdgcn_readfirstlane(node);
  const int start = __builtin_amdgcn_readfirstlane(rowptr[nu]);
  const int end   = __builtin_amdgcn_readfirstlane(rowptr[nu + 1]);
  const uint4* __restrict__ m1q = (const uint4*)m1;  // row = 8 uint4 (128B)
  const int g = lane >> 3;  // edge slot 0..7 within 8-edge group
  const int q = lane & 7;   // uint4 index in row -> features 8q..8q+7
  float a0=0.f,a1=0.f,a2=0.f,a3=0.f,a4=0.f,a5=0.f,a6=0.f,a7=0.f;
  for (int base = start; base < end; base += 64) {
    int m = min(64, end - base);
    int sv = (lane < m) ? csr_src[base + lane] : 0;  // coalesced id read
    for (int j = 0; j < m; j += 8) {
      int idx = j + g;
      int s = __shfl(sv, min(idx, m - 1));
      if (idx < m) {                                  // uniform-true except tail
        uint4 v = m1q[(size_t)s * 8 + q];             // 1 load = 8 edge-rows/wave
        a0 += __uint_as_float(v.x << 16);
        a1 += __uint_as_float(v.x & 0xffff0000u);
        a2 += __uint_as_float(v.y << 16);
        a3 += __uint_as_float(v.y & 0xffff0000u);
        a4 += __uint_as_float(v.z << 16);
        a5 += __uint_as_float(v.z & 0xffff0000u);
        a6 += __uint_as_float(v.w << 16);
        a7 += __uint_as_float(v.w & 0xffff0000u);
      }
    }
  }
  // combine 8 edge-groups (lane bits 3..5)
#pragma unroll
  for (int off = 32; off >= 8; off >>= 1) {
    a0 += __shfl_xor(a0, off); a1 += __shfl_xor(a1, off);
    a2 += __shfl_xor(a2, off); a3 += __shfl_xor(a3, off);
    a4 += __shfl_xor(a4, off); a5 += __shfl_xor(a5, off);
    a6 += __shfl_xor(a6, off); a7 += __shfl_xor(a7, off);
  }
  {  // self-loop row (replicated consistently across groups)
    uint4 v = m1q[(size_t)nu * 8 + q];
    a0 += __uint_as_float(v.x << 16);
    a1 += __uint_as_float(v.x & 0xffff0000u);
    a2 += __uint_as_float(v.y << 16);
    a3 += __uint_as_float(v.y & 0xffff0000u);
    a4 += __uint_as_float(v.z << 16);
    a5 += __uint_as_float(v.z & 0xffff0000u);
    a6 += __uint_as_float(v.w << 16);
    a7 += __uint_as_float(v.w & 0xffff0000u);
  }
  const float dv = dinv[nu];
  const float4 bva = ((const float4*)b1)[q * 2 + 0];   // b1[8q..8q+3]
  const float4 bvb = ((const float4*)b1)[q * 2 + 1];   // b1[8q+4..8q+7]
  // W2[64][2] row-major: float4 i covers rows 2i,2i+1. Rows 8q..8q+7 = idx 4q..4q+3.
  const float4 wA = ((const float4*)W2)[q * 4 + 0];
  const float4 wB = ((const float4*)W2)[q * 4 + 1];
  const float4 wC = ((const float4*)W2)[q * 4 + 2];
  const float4 wD = ((const float4*)W2)[q * 4 + 3];
  float h0 = fmaxf(fmaf(a0, dv, bva.x), 0.f);
  float h1 = fmaxf(fmaf(a1, dv, bva.y), 0.f);
  float h2 = fmaxf(fmaf(a2, dv, bva.z), 0.f);
  float h3 = fmaxf(fmaf(a3, dv, bva.w), 0.f);
  float h4 = fmaxf(fmaf(a4, dv, bvb.x), 0.f);
  float h5 = fmaxf(fmaf(a5, dv, bvb.y), 0.f);
  float h6 = fmaxf(fmaf(a6, dv, bvb.z), 0.f);
  float h7 = fmaxf(fmaf(a7, dv, bvb.w), 0.f);
  float p0 = h0 * wA.x + h1 * wA.z + h2 * wB.x + h3 * wB.z
           + h4 * wC.x + h5 * wC.z + h6 * wD.x + h7 * wD.z;
  float p1 = h0 * wA.y + h1 * wA.w + h2 * wB.y + h3 * wB.w
           + h4 * wC.y + h5 * wC.w + h6 * wD.y + h7 * wD.w;
#pragma unroll
  for (int off = 4; off; off >>= 1) {  // reduce over q (lane bits 0..2)
    p0 += __shfl_xor(p0, off);
    p1 += __shfl_xor(p1, off);
  }
  if (lane == 0) {
    m2[nu * 2 + 0] = p0 * dv;
    m2[nu * 2 + 1] = p1 * dv;
  }
}

// ---- conv2: wave-per-node light gather + bias + generator mask ----
__global__ __launch_bounds__(256) void k_agg2(const float* __restrict__ m2,
                                              const int* __restrict__ rowptr,
                                              const int* __restrict__ csr_src,
                                              const float* __restrict__ dinv,
                                              const float* __restrict__ b2,
                                              const float* __restrict__ x,
                                              float* __restrict__ out) {
  int node = blockIdx.x * 4 + (threadIdx.x >> 6);
  if (node >= N) return;
  int lane = threadIdx.x & 63;
  int nu = __builtin_amdgcn_readfirstlane(node);
  int start = __builtin_amdgcn_readfirstlane(rowptr[nu]);
  int end   = __builtin_amdgcn_readfirstlane(rowptr[nu + 1]);
  float a0 = 0.f, a1 = 0.f;
  for (int e = start + lane; e < end; e += 64) {
    int s = csr_src[e];
    a0 += m2[s * 2 + 0];
    a1 += m2[s * 2 + 1];
  }
#pragma unroll
  for (int off = 32; off; off >>= 1) {
    a0 += __shfl_xor(a0, off);
    a1 += __shfl_xor(a1, off);
  }
  if (lane == 0) {
    a0 += m2[nu * 2 + 0];  // self-loop
    a1 += m2[nu * 2 + 1];
    float dv = dinv[nu];
    float o0 = a0 * dv + b2[0];
    float o1 = a1 * dv + b2[1];
    float msk = (x[(size_t)nu * FIN] == 1.0f) ? 1.0f : 0.0f;
    out[nu * 2 + 0] = o0 * msk;
    out[nu * 2 + 1] = o1 * msk;
  }
}

extern "C" void kernel_launch(void* const* d_in, const int* in_sizes, int n_in,
                              void* d_out, int out_size, void* d_ws, size_t ws_size,
                              hipStream_t stream) {
  const float* x   = (const float*)d_in[0];
  const int*   ei  = (const int*)d_in[1];  // int32 [2, E] flat
  const float* W1  = (const float*)d_in[2];
  const float* b1  = (const float*)d_in[3];
  const float* W2  = (const float*)d_in[4];
  const float* b2  = (const float*)d_in[5];
  float*       out = (float*)d_out;

  char* w = (char*)d_ws;
  auto alloc = [&](size_t bytes) -> char* {
    char* p = w;
    w += (bytes + 255) & ~(size_t)255;
    return p;
  };
  int*            rowptr  = (int*)alloc((size_t)(N + 1) * 4);
  float*          dinv    = (float*)alloc((size_t)N * 4);
  unsigned*       binned  = (unsigned*)alloc((size_t)E * 4);
  int*            segCnt  = (int*)alloc((size_t)NB * NC * 4);
  int*            lp      = (int*)alloc((size_t)NB * NC * 4);
  int*            binTot  = (int*)alloc((size_t)NB * 4);
  int*            binBase = (int*)alloc((size_t)(NB + 1) * 4);
  int*            csr_src = (int*)alloc((size_t)E * 4);
  __hip_bfloat16* m1      = (__hip_bfloat16*)alloc((size_t)N * FH * 2);
  float*          m2      = (float*)alloc((size_t)N * 2 * 4);

  const int* srcA = ei;      // edge_index[0]
  const int* dstA = ei + E;  // edge_index[1]

  k_cnt<<<dim3(NC), dim3(512), 0, stream>>>(dstA, segCnt);
  k_chunkScan<<<dim3(NB), dim3(512), 0, stream>>>(segCnt, lp, binTot);
  k_binScan<<<dim3(1), dim3(64), 0, stream>>>(binTot, binBase, rowptr);
  k_scat<<<dim3(NC), dim3(512), 0, stream>>>(srcA, dstA, lp, binBase, binned);
  k_fill4<<<dim3(NB), dim3(512), 0, stream>>>(binned, binBase, rowptr, dinv, csr_src);
  k_gemm1<<<dim3(N / 16), dim3(256), 0, stream>>>(x, W1, dinv, m1);  // 6250 blocks
  k_agg1<<<dim3((N + 3) / 4), dim3(256), 0, stream>>>(m1, rowptr, csr_src, dinv, b1, W2, m2);
  k_agg2<<<dim3((N + 3) / 4), dim3(256), 0, stream>>>(m2, rowptr, csr_src, dinv, b2, x, out);
}

// Round 10
// 170.999 us; speedup vs baseline: 9.9970x; 1.1526x over previous
//
#include <hip/hip_runtime.h>
#include <hip/hip_bf16.h>
#include <math.h>

// GCN 2-layer forward on MI355X — v10.
// v9 post-mortem: agg1's epilogue (~120 VALU/node) rivals its inner loop at
// avg degree 32; id-read batches half-empty. v10: 2 nodes per wave (one per
// 32-lane half) — epilogue shared, combine 24->16 ops, 32-wide id batches.
// Pipeline: cnt -> chunkScan -> binScan -> scat -> fill4 -> gemm1 -> agg1 -> agg2.

constexpr int N   = 100000;
constexpr int E   = 3200000;
constexpr int FIN = 128;
constexpr int FH  = 64;

constexpr int NPB = 256;                      // nodes per bin
constexpr int NB  = (N + NPB - 1) / NPB;      // 391 bins
constexpr int K   = 6400;                     // edges per chunk
constexpr int NC  = E / K;                    // 500 chunks (exact)

// ---- 1: per-(chunk,bin) counts, bin-major layout ----
__global__ __launch_bounds__(512) void k_cnt(const int* __restrict__ dstA,
                                             int* __restrict__ segCnt) {
  __shared__ int bc[NB];
  const int w = blockIdx.x;
  const int base = w * K;
  for (int i = threadIdx.x; i < NB; i += 512) bc[i] = 0;
  __syncthreads();
  for (int i = threadIdx.x; i < K; i += 512)
    atomicAdd(&bc[dstA[base + i] >> 8], 1);
  __syncthreads();
  for (int b = threadIdx.x; b < NB; b += 512) segCnt[b * NC + w] = bc[b];
}

// ---- 2: per-bin exclusive scan over chunks -> lp, binTot ----
__global__ __launch_bounds__(512) void k_chunkScan(const int* __restrict__ segCnt,
                                                   int* __restrict__ lp,
                                                   int* __restrict__ binTot) {
  __shared__ int sh[512];
  const int b = blockIdx.x;
  const int t = threadIdx.x;
  int v = (t < NC) ? segCnt[b * NC + t] : 0;
  sh[t] = v;
  __syncthreads();
  for (int off = 1; off < 512; off <<= 1) {
    int tv = (t >= off) ? sh[t - off] : 0;
    __syncthreads();
    sh[t] += tv;
    __syncthreads();
  }
  if (t < NC) lp[b * NC + t] = sh[t] - v;   // exclusive prefix
  if (t == 511) binTot[b] = sh[511];
}

// ---- 3: tiny serial scan over 391 bins ----
__global__ void k_binScan(const int* __restrict__ binTot,
                          int* __restrict__ binBase, int* __restrict__ rowptr) {
  if (threadIdx.x == 0 && blockIdx.x == 0) {
    int s = 0;
    for (int b = 0; b < NB; ++b) { binBase[b] = s; s += binTot[b]; }
    binBase[NB] = s;
    rowptr[N] = s;  // == E
  }
}

// ---- 4: scatter edges into contiguous bin-major windows ----
__global__ __launch_bounds__(512) void k_scat(const int* __restrict__ srcA,
                                              const int* __restrict__ dstA,
                                              const int* __restrict__ lp,
                                              const int* __restrict__ binBase,
                                              unsigned* __restrict__ binned) {
  __shared__ int lpw[NB];
  __shared__ int cur[NB];
  const int w = blockIdx.x;
  const int base = w * K;
  for (int b = threadIdx.x; b < NB; b += 512) {
    lpw[b] = binBase[b] + lp[b * NC + w];
    cur[b] = 0;
  }
  __syncthreads();
  for (int i = threadIdx.x; i < K; i += 512) {
    int s = srcA[base + i];
    int d = dstA[base + i];
    int b = d >> 8;
    int slot = lpw[b] + atomicAdd(&cur[b], 1);  // WG dirty set ~391 lines: L2-held
    binned[slot] = ((unsigned)(d & 255) << 17) | (unsigned)s;  // src<2^17, dl<2^8
  }
}

// ---- 5: per-bin CSR from contiguous window: count, scan, place ----
__global__ __launch_bounds__(512) void k_fill4(const unsigned* __restrict__ binned,
                                               const int* __restrict__ binBase,
                                               int* __restrict__ rowptr,
                                               float* __restrict__ dinv,
                                               int* __restrict__ csr_src) {
  __shared__ int cnt_s[NPB];
  __shared__ int sh[NPB];
  __shared__ int cur[NPB];
  const int b = blockIdx.x;
  const int t = threadIdx.x;
  const int w0 = binBase[b], w1 = binBase[b + 1];
  if (t < NPB) cnt_s[t] = 0;
  __syncthreads();
  for (int i = w0 + t; i < w1; i += 512)     // dense coalesced stream
    atomicAdd(&cnt_s[binned[i] >> 17], 1);
  __syncthreads();
  int v = 0;
  if (t < NPB) { v = cnt_s[t]; sh[t] = v; }
  __syncthreads();
  for (int off = 1; off < NPB; off <<= 1) {  // Hillis-Steele inclusive
    int tv = (t < NPB && t >= off) ? sh[t - off] : 0;
    __syncthreads();
    if (t < NPB) sh[t] += tv;
    __syncthreads();
  }
  if (t < NPB) {
    int node = b * NPB + t;
    int start = w0 + sh[t] - v;              // exclusive prefix within window
    if (node < N) {
      rowptr[node] = start;
      dinv[node] = 1.0f / sqrtf((float)(v + 1));  // +1 self-loop
    }
    cur[t] = start;
  }
  __syncthreads();
  for (int i = w0 + t; i < w1; i += 512) {   // re-read (L2-hot), place by node
    unsigned e = binned[i];
    int p = atomicAdd(&cur[e >> 17], 1);
    csr_src[p] = (int)(e & 0x1FFFFu);        // scatter confined to ~33KB window
  }
}

// ---- m1[n, f] = bf16((x[n,:] @ W1[:,f]) * dinv[n]); 4 nodes/wave ----
__global__ __launch_bounds__(256) void k_gemm1(const float* __restrict__ x,
                                               const float* __restrict__ W1,
                                               const float* __restrict__ dinv,
                                               __hip_bfloat16* __restrict__ m1) {
  __shared__ float W1s[FIN * FH];  // 32 KB
  for (int i = threadIdx.x; i < FIN * FH; i += 256) W1s[i] = W1[i];
  __syncthreads();
  const int lane = threadIdx.x & 63;
  const int wv = threadIdx.x >> 6;  // 0..3
  // 4 nodes per wave, 16 per block; N == 6250*16 exactly (no tail).
  const int nb = __builtin_amdgcn_readfirstlane((blockIdx.x * 4 + wv) * 4);
  const float* xr0 = x + (size_t)(nb + 0) * FIN;
  const float* xr1 = x + (size_t)(nb + 1) * FIN;
  const float* xr2 = x + (size_t)(nb + 2) * FIN;
  const float* xr3 = x + (size_t)(nb + 3) * FIN;
  float acc0 = 0.f, acc1 = 0.f, acc2 = 0.f, acc3 = 0.f;
#pragma unroll
  for (int k = 0; k < FIN; k += 4) {
    float w0 = W1s[(k + 0) * FH + lane];
    float w1 = W1s[(k + 1) * FH + lane];
    float w2 = W1s[(k + 2) * FH + lane];
    float w3 = W1s[(k + 3) * FH + lane];
    acc0 = fmaf(xr0[k + 0], w0, acc0); acc1 = fmaf(xr1[k + 0], w0, acc1);
    acc2 = fmaf(xr2[k + 0], w0, acc2); acc3 = fmaf(xr3[k + 0], w0, acc3);
    acc0 = fmaf(xr0[k + 1], w1, acc0); acc1 = fmaf(xr1[k + 1], w1, acc1);
    acc2 = fmaf(xr2[k + 1], w1, acc2); acc3 = fmaf(xr3[k + 1], w1, acc3);
    acc0 = fmaf(xr0[k + 2], w2, acc0); acc1 = fmaf(xr1[k + 2], w2, acc1);
    acc2 = fmaf(xr2[k + 2], w2, acc2); acc3 = fmaf(xr3[k + 2], w2, acc3);
    acc0 = fmaf(xr0[k + 3], w3, acc0); acc1 = fmaf(xr1[k + 3], w3, acc1);
    acc2 = fmaf(xr2[k + 3], w3, acc2); acc3 = fmaf(xr3[k + 3], w3, acc3);
  }
  m1[(size_t)(nb + 0) * FH + lane] = __float2bfloat16(acc0 * dinv[nb + 0]);
  m1[(size_t)(nb + 1) * FH + lane] = __float2bfloat16(acc1 * dinv[nb + 1]);
  m1[(size_t)(nb + 2) * FH + lane] = __float2bfloat16(acc2 * dinv[nb + 2]);
  m1[(size_t)(nb + 3) * FH + lane] = __float2bfloat16(acc3 * dinv[nb + 3]);
}

// ---- conv1: 2 nodes/wave (one per 32-lane half), 8 edges per wave-load ----
__global__ __launch_bounds__(256) void k_agg1(const __hip_bfloat16* __restrict__ m1,
                                              const int* __restrict__ rowptr,
                                              const int* __restrict__ csr_src,
                                              const float* __restrict__ dinv,
                                              const float* __restrict__ b1,
                                              const float* __restrict__ W2,
                                              float* __restrict__ m2) {
  const int lane = threadIdx.x & 63;
  const int half = lane >> 5;                 // 0 = node A, 1 = node B
  const int node = blockIdx.x * 8 + (threadIdx.x >> 6) * 2 + half;  // exact grid
  const int g2 = (lane >> 3) & 3;             // edge subslot 0..3 within half
  const int q  = lane & 7;                    // uint4 index -> features 8q..8q+7
  const int s0 = rowptr[node];                // uniform per half
  const int deg = rowptr[node + 1] - s0;
  const uint4* __restrict__ m1q = (const uint4*)m1;  // row = 8 uint4 (128B)
  float a0=0.f,a1=0.f,a2=0.f,a3=0.f,a4=0.f,a5=0.f,a6=0.f,a7=0.f;
  const int i = lane & 31;                    // id slot within half's batch
  for (int base = 0;; base += 32) {
    int rem = deg - base;                     // uniform per half
    if (__all(rem <= 0)) break;
    int sv = (i < rem) ? csr_src[s0 + base + i] : 0;  // 32 ids per node
#pragma unroll
    for (int j = 0; j < 32; j += 8) {
      int idx = j + g2;
      int s = __shfl(sv, (half << 5) | idx);  // id from own half
      if (idx < rem) {                        // near-uniform predicate
        uint4 v = m1q[(size_t)s * 8 + q];     // 1 load = 8 edge-rows/wave
        a0 += __uint_as_float(v.x << 16);
        a1 += __uint_as_float(v.x & 0xffff0000u);
        a2 += __uint_as_float(v.y << 16);
        a3 += __uint_as_float(v.y & 0xffff0000u);
        a4 += __uint_as_float(v.z << 16);
        a5 += __uint_as_float(v.z & 0xffff0000u);
        a6 += __uint_as_float(v.w << 16);
        a7 += __uint_as_float(v.w & 0xffff0000u);
      }
    }
  }
  // combine 4 edge-subslots (lane bits 3..4) — stays within each half
#pragma unroll
  for (int off = 8; off <= 16; off <<= 1) {
    a0 += __shfl_xor(a0, off); a1 += __shfl_xor(a1, off);
    a2 += __shfl_xor(a2, off); a3 += __shfl_xor(a3, off);
    a4 += __shfl_xor(a4, off); a5 += __shfl_xor(a5, off);
    a6 += __shfl_xor(a6, off); a7 += __shfl_xor(a7, off);
  }
  {  // self-loop row (per-lane address by half's node)
    uint4 v = m1q[(size_t)node * 8 + q];
    a0 += __uint_as_float(v.x << 16);
    a1 += __uint_as_float(v.x & 0xffff0000u);
    a2 += __uint_as_float(v.y << 16);
    a3 += __uint_as_float(v.y & 0xffff0000u);
    a4 += __uint_as_float(v.z << 16);
    a5 += __uint_as_float(v.z & 0xffff0000u);
    a6 += __uint_as_float(v.w << 16);
    a7 += __uint_as_float(v.w & 0xffff0000u);
  }
  const float dv = dinv[node];
  const float4 bva = ((const float4*)b1)[q * 2 + 0];   // b1[8q..8q+3]
  const float4 bvb = ((const float4*)b1)[q * 2 + 1];   // b1[8q+4..8q+7]
  // W2[64][2] row-major: float4 i covers rows 2i,2i+1. Rows 8q..8q+7 = idx 4q..4q+3.
  const float4 wA = ((const float4*)W2)[q * 4 + 0];
  const float4 wB = ((const float4*)W2)[q * 4 + 1];
  const float4 wC = ((const float4*)W2)[q * 4 + 2];
  const float4 wD = ((const float4*)W2)[q * 4 + 3];
  float h0 = fmaxf(fmaf(a0, dv, bva.x), 0.f);
  float h1 = fmaxf(fmaf(a1, dv, bva.y), 0.f);
  float h2 = fmaxf(fmaf(a2, dv, bva.z), 0.f);
  float h3 = fmaxf(fmaf(a3, dv, bva.w), 0.f);
  float h4 = fmaxf(fmaf(a4, dv, bvb.x), 0.f);
  float h5 = fmaxf(fmaf(a5, dv, bvb.y), 0.f);
  float h6 = fmaxf(fmaf(a6, dv, bvb.z), 0.f);
  float h7 = fmaxf(fmaf(a7, dv, bvb.w), 0.f);
  float p0 = h0 * wA.x + h1 * wA.z + h2 * wB.x + h3 * wB.z
           + h4 * wC.x + h5 * wC.z + h6 * wD.x + h7 * wD.z;
  float p1 = h0 * wA.y + h1 * wA.w + h2 * wB.y + h3 * wB.w
           + h4 * wC.y + h5 * wC.w + h6 * wD.y + h7 * wD.w;
#pragma unroll
  for (int off = 4; off; off >>= 1) {  // reduce over q (lane bits 0..2)
    p0 += __shfl_xor(p0, off);
    p1 += __shfl_xor(p1, off);
  }
  if ((lane & 31) == 0) {              // lane 0 -> node A, lane 32 -> node B
    m2[node * 2 + 0] = p0 * dv;
    m2[node * 2 + 1] = p1 * dv;
  }
}

// ---- conv2: 2 nodes/wave light gather + bias + generator mask ----
__global__ __launch_bounds__(256) void k_agg2(const float* __restrict__ m2,
                                              const int* __restrict__ rowptr,
                                              const int* __restrict__ csr_src,
                                              const float* __restrict__ dinv,
                                              const float* __restrict__ b2,
                                              const float* __restrict__ x,
                                              float* __restrict__ out) {
  const int lane = threadIdx.x & 63;
  const int half = lane >> 5;
  const int node = blockIdx.x * 8 + (threadIdx.x >> 6) * 2 + half;  // exact grid
  const int s0 = rowptr[node];
  const int e0 = rowptr[node + 1];
  float a0 = 0.f, a1 = 0.f;
  for (int e = s0 + (lane & 31); e < e0; e += 32) {
    int s = csr_src[e];
    a0 += m2[s * 2 + 0];
    a1 += m2[s * 2 + 1];
  }
#pragma unroll
  for (int off = 16; off; off >>= 1) {   // reduce within half
    a0 += __shfl_xor(a0, off);
    a1 += __shfl_xor(a1, off);
  }
  if ((lane & 31) == 0) {
    a0 += m2[node * 2 + 0];  // self-loop
    a1 += m2[node * 2 + 1];
    float dv = dinv[node];
    float o0 = a0 * dv + b2[0];
    float o1 = a1 * dv + b2[1];
    float msk = (x[(size_t)node * FIN] == 1.0f) ? 1.0f : 0.0f;
    out[node * 2 + 0] = o0 * msk;
    out[node * 2 + 1] = o1 * msk;
  }
}

extern "C" void kernel_launch(void* const* d_in, const int* in_sizes, int n_in,
                              void* d_out, int out_size, void* d_ws, size_t ws_size,
                              hipStream_t stream) {
  const float* x   = (const float*)d_in[0];
  const int*   ei  = (const int*)d_in[1];  // int32 [2, E] flat
  const float* W1  = (const float*)d_in[2];
  const float* b1  = (const float*)d_in[3];
  const float* W2  = (const float*)d_in[4];
  const float* b2  = (const float*)d_in[5];
  float*       out = (float*)d_out;

  char* w = (char*)d_ws;
  auto alloc = [&](size_t bytes) -> char* {
    char* p = w;
    w += (bytes + 255) & ~(size_t)255;
    return p;
  };
  int*            rowptr  = (int*)alloc((size_t)(N + 1) * 4);
  float*          dinv    = (float*)alloc((size_t)N * 4);
  unsigned*       binned  = (unsigned*)alloc((size_t)E * 4);
  int*            segCnt  = (int*)alloc((size_t)NB * NC * 4);
  int*            lp      = (int*)alloc((size_t)NB * NC * 4);
  int*            binTot  = (int*)alloc((size_t)NB * 4);
  int*            binBase = (int*)alloc((size_t)(NB + 1) * 4);
  int*            csr_src = (int*)alloc((size_t)E * 4);
  __hip_bfloat16* m1      = (__hip_bfloat16*)alloc((size_t)N * FH * 2);
  float*          m2      = (float*)alloc((size_t)N * 2 * 4);

  const int* srcA = ei;      // edge_index[0]
  const int* dstA = ei + E;  // edge_index[1]

  k_cnt<<<dim3(NC), dim3(512), 0, stream>>>(dstA, segCnt);
  k_chunkScan<<<dim3(NB), dim3(512), 0, stream>>>(segCnt, lp, binTot);
  k_binScan<<<dim3(1), dim3(64), 0, stream>>>(binTot, binBase, rowptr);
  k_scat<<<dim3(NC), dim3(512), 0, stream>>>(srcA, dstA, lp, binBase, binned);
  k_fill4<<<dim3(NB), dim3(512), 0, stream>>>(binned, binBase, rowptr, dinv, csr_src);
  k_gemm1<<<dim3(N / 16), dim3(256), 0, stream>>>(x, W1, dinv, m1);  // 6250 blocks
  k_agg1<<<dim3(N / 8), dim3(256), 0, stream>>>(m1, rowptr, csr_src, dinv, b1, W2, m2);  // 12500
  k_agg2<<<dim3(N / 8), dim3(256), 0, stream>>>(m2, rowptr, csr_src, dinv, b2, x, out);  // 12500
}

// Round 11
// 145.685 us; speedup vs baseline: 11.7341x; 1.1738x over previous
//
#include <hip/hip_runtime.h>
#include <hip/hip_bf16.h>
#include <math.h>

// GCN 2-layer forward on MI355X — v11.
// v10 post-mortem: k_gemm1 (61us) was serialized by wave-uniform scalar x
// loads (SMEM out-of-order => lgkmcnt(0) drains, ~32 HBM sync points/wave).
// v11: MFMA GEMM — coalesced vector A loads (f32->bf16 in-reg), W1 bf16
// fragment-major in LDS, 16x mfma_f32_16x16x32_bf16 per 16-node tile.
// Pipeline: cnt -> chunkScan -> binScan -> scat -> fill4 -> gemm1(MFMA) ->
//           agg1 -> agg2.

constexpr int N   = 100000;
constexpr int E   = 3200000;
constexpr int FIN = 128;
constexpr int FH  = 64;

constexpr int NPB = 256;                      // nodes per bin
constexpr int NB  = (N + NPB - 1) / NPB;      // 391 bins
constexpr int K   = 6400;                     // edges per chunk
constexpr int NC  = E / K;                    // 500 chunks (exact)

typedef __attribute__((ext_vector_type(8))) short short8;   // 8 bf16 (4 VGPR)
typedef __attribute__((ext_vector_type(4))) float f32x4;    // MFMA acc

__device__ inline short f2bf(float f) {       // f32 -> bf16 (round-nearest-even)
  unsigned u = __float_as_uint(f);
  return (short)((u + 0x7FFFu + ((u >> 16) & 1u)) >> 16);
}

// ---- 1: per-(chunk,bin) counts, bin-major layout ----
__global__ __launch_bounds__(512) void k_cnt(const int* __restrict__ dstA,
                                             int* __restrict__ segCnt) {
  __shared__ int bc[NB];
  const int w = blockIdx.x;
  const int base = w * K;
  for (int i = threadIdx.x; i < NB; i += 512) bc[i] = 0;
  __syncthreads();
  for (int i = threadIdx.x; i < K; i += 512)
    atomicAdd(&bc[dstA[base + i] >> 8], 1);
  __syncthreads();
  for (int b = threadIdx.x; b < NB; b += 512) segCnt[b * NC + w] = bc[b];
}

// ---- 2: per-bin exclusive scan over chunks -> lp, binTot ----
__global__ __launch_bounds__(512) void k_chunkScan(const int* __restrict__ segCnt,
                                                   int* __restrict__ lp,
                                                   int* __restrict__ binTot) {
  __shared__ int sh[512];
  const int b = blockIdx.x;
  const int t = threadIdx.x;
  int v = (t < NC) ? segCnt[b * NC + t] : 0;
  sh[t] = v;
  __syncthreads();
  for (int off = 1; off < 512; off <<= 1) {
    int tv = (t >= off) ? sh[t - off] : 0;
    __syncthreads();
    sh[t] += tv;
    __syncthreads();
  }
  if (t < NC) lp[b * NC + t] = sh[t] - v;   // exclusive prefix
  if (t == 511) binTot[b] = sh[511];
}

// ---- 3: tiny serial scan over 391 bins ----
__global__ void k_binScan(const int* __restrict__ binTot,
                          int* __restrict__ binBase, int* __restrict__ rowptr) {
  if (threadIdx.x == 0 && blockIdx.x == 0) {
    int s = 0;
    for (int b = 0; b < NB; ++b) { binBase[b] = s; s += binTot[b]; }
    binBase[NB] = s;
    rowptr[N] = s;  // == E
  }
}

// ---- 4: scatter edges into contiguous bin-major windows ----
__global__ __launch_bounds__(512) void k_scat(const int* __restrict__ srcA,
                                              const int* __restrict__ dstA,
                                              const int* __restrict__ lp,
                                              const int* __restrict__ binBase,
                                              unsigned* __restrict__ binned) {
  __shared__ int lpw[NB];
  __shared__ int cur[NB];
  const int w = blockIdx.x;
  const int base = w * K;
  for (int b = threadIdx.x; b < NB; b += 512) {
    lpw[b] = binBase[b] + lp[b * NC + w];
    cur[b] = 0;
  }
  __syncthreads();
  for (int i = threadIdx.x; i < K; i += 512) {
    int s = srcA[base + i];
    int d = dstA[base + i];
    int b = d >> 8;
    int slot = lpw[b] + atomicAdd(&cur[b], 1);  // WG dirty set ~391 lines: L2-held
    binned[slot] = ((unsigned)(d & 255) << 17) | (unsigned)s;  // src<2^17, dl<2^8
  }
}

// ---- 5: per-bin CSR from contiguous window: count, scan, place ----
__global__ __launch_bounds__(512) void k_fill4(const unsigned* __restrict__ binned,
                                               const int* __restrict__ binBase,
                                               int* __restrict__ rowptr,
                                               float* __restrict__ dinv,
                                               int* __restrict__ csr_src) {
  __shared__ int cnt_s[NPB];
  __shared__ int sh[NPB];
  __shared__ int cur[NPB];
  const int b = blockIdx.x;
  const int t = threadIdx.x;
  const int w0 = binBase[b], w1 = binBase[b + 1];
  if (t < NPB) cnt_s[t] = 0;
  __syncthreads();
  for (int i = w0 + t; i < w1; i += 512)     // dense coalesced stream
    atomicAdd(&cnt_s[binned[i] >> 17], 1);
  __syncthreads();
  int v = 0;
  if (t < NPB) { v = cnt_s[t]; sh[t] = v; }
  __syncthreads();
  for (int off = 1; off < NPB; off <<= 1) {  // Hillis-Steele inclusive
    int tv = (t < NPB && t >= off) ? sh[t - off] : 0;
    __syncthreads();
    if (t < NPB) sh[t] += tv;
    __syncthreads();
  }
  if (t < NPB) {
    int node = b * NPB + t;
    int start = w0 + sh[t] - v;              // exclusive prefix within window
    if (node < N) {
      rowptr[node] = start;
      dinv[node] = 1.0f / sqrtf((float)(v + 1));  // +1 self-loop
    }
    cur[t] = start;
  }
  __syncthreads();
  for (int i = w0 + t; i < w1; i += 512) {   // re-read (L2-hot), place by node
    unsigned e = binned[i];
    int p = atomicAdd(&cur[e >> 17], 1);
    csr_src[p] = (int)(e & 0x1FFFFu);        // scatter confined to ~33KB window
  }
}

// ---- m1 = bf16((x @ W1) * dinv) via MFMA; wave = 16-node tile ----
__global__ __launch_bounds__(256) void k_gemm1(const float* __restrict__ x,
                                               const float* __restrict__ W1,
                                               const float* __restrict__ dinv,
                                               __hip_bfloat16* __restrict__ m1) {
  // B-fragments of W1 in LDS, frag-major: frag (s*4+j), lane l holds
  // W1[32s + 8*(l>>4) + e][16j + (l&15)] as bf16x8 -> ds_read_b128.
  __shared__ short8 W1f[16 * 64];  // 16 KB
  const int t = threadIdx.x;
  for (int i = t; i < 16 * 64; i += 256) {
    int frag = i >> 6, l = i & 63;
    int s = frag >> 2, j = frag & 3;
    int kb = 32 * s + 8 * (l >> 4);
    int f  = 16 * j + (l & 15);
    short8 v;
#pragma unroll
    for (int e = 0; e < 8; ++e) v[e] = f2bf(W1[(kb + e) * FH + f]);
    W1f[i] = v;
  }
  __syncthreads();
  const int lane = t & 63;
  const int r16 = lane & 15;   // A row within tile / D col
  const int g4  = lane >> 4;   // k-group
  const int nWaves = gridDim.x * 4;
  const int wid = blockIdx.x * 4 + (t >> 6);
  unsigned short* __restrict__ m1u = (unsigned short*)m1;
  for (int T = wid; T < N / 16; T += nWaves) {
    const float* xrow = x + (size_t)(16 * T + r16) * FIN + 8 * g4;
    f32x4 acc0 = {0,0,0,0}, acc1 = {0,0,0,0}, acc2 = {0,0,0,0}, acc3 = {0,0,0,0};
#pragma unroll
    for (int s = 0; s < 4; ++s) {
      float4 fa = *(const float4*)(xrow + 32 * s);       // coalesced, vmcnt-pipelined
      float4 fb = *(const float4*)(xrow + 32 * s + 4);
      short8 a;
      a[0] = f2bf(fa.x); a[1] = f2bf(fa.y); a[2] = f2bf(fa.z); a[3] = f2bf(fa.w);
      a[4] = f2bf(fb.x); a[5] = f2bf(fb.y); a[6] = f2bf(fb.z); a[7] = f2bf(fb.w);
      acc0 = __builtin_amdgcn_mfma_f32_16x16x32_bf16(a, W1f[(s*4+0)*64 + lane], acc0, 0, 0, 0);
      acc1 = __builtin_amdgcn_mfma_f32_16x16x32_bf16(a, W1f[(s*4+1)*64 + lane], acc1, 0, 0, 0);
      acc2 = __builtin_amdgcn_mfma_f32_16x16x32_bf16(a, W1f[(s*4+2)*64 + lane], acc2, 0, 0, 0);
      acc3 = __builtin_amdgcn_mfma_f32_16x16x32_bf16(a, W1f[(s*4+3)*64 + lane], acc3, 0, 0, 0);
    }
    // D layout: col = lane&15, row = 4*(lane>>4)+reg  [verified mapping]
    const int nodeBase = 16 * T + 4 * g4;
    float dv0 = dinv[nodeBase + 0];
    float dv1 = dinv[nodeBase + 1];
    float dv2 = dinv[nodeBase + 2];
    float dv3 = dinv[nodeBase + 3];
#pragma unroll
    for (int j = 0; j < 4; ++j) {
      f32x4 acc = (j == 0) ? acc0 : (j == 1) ? acc1 : (j == 2) ? acc2 : acc3;
      size_t fcol = 16 * j + r16;
      m1u[(size_t)(nodeBase + 0) * FH + fcol] = (unsigned short)f2bf(acc[0] * dv0);
      m1u[(size_t)(nodeBase + 1) * FH + fcol] = (unsigned short)f2bf(acc[1] * dv1);
      m1u[(size_t)(nodeBase + 2) * FH + fcol] = (unsigned short)f2bf(acc[2] * dv2);
      m1u[(size_t)(nodeBase + 3) * FH + fcol] = (unsigned short)f2bf(acc[3] * dv3);
    }
  }
}

// ---- conv1: 2 nodes/wave (one per 32-lane half), 8 edges per wave-load ----
__global__ __launch_bounds__(256) void k_agg1(const __hip_bfloat16* __restrict__ m1,
                                              const int* __restrict__ rowptr,
                                              const int* __restrict__ csr_src,
                                              const float* __restrict__ dinv,
                                              const float* __restrict__ b1,
                                              const float* __restrict__ W2,
                                              float* __restrict__ m2) {
  const int lane = threadIdx.x & 63;
  const int half = lane >> 5;                 // 0 = node A, 1 = node B
  const int node = blockIdx.x * 8 + (threadIdx.x >> 6) * 2 + half;  // exact grid
  const int g2 = (lane >> 3) & 3;             // edge subslot 0..3 within half
  const int q  = lane & 7;                    // uint4 index -> features 8q..8q+7
  const int s0 = rowptr[node];                // uniform per half
  const int deg = rowptr[node + 1] - s0;
  const uint4* __restrict__ m1q = (const uint4*)m1;  // row = 8 uint4 (128B)
  float a0=0.f,a1=0.f,a2=0.f,a3=0.f,a4=0.f,a5=0.f,a6=0.f,a7=0.f;
  const int i = lane & 31;                    // id slot within half's batch
  for (int base = 0;; base += 32) {
    int rem = deg - base;                     // uniform per half
    if (__all(rem <= 0)) break;
    int sv = (i < rem) ? csr_src[s0 + base + i] : 0;  // 32 ids per node
#pragma unroll
    for (int j = 0; j < 32; j += 8) {
      int idx = j + g2;
      int s = __shfl(sv, (half << 5) | idx);  // id from own half
      if (idx < rem) {                        // near-uniform predicate
        uint4 v = m1q[(size_t)s * 8 + q];     // 1 load = 8 edge-rows/wave
        a0 += __uint_as_float(v.x << 16);
        a1 += __uint_as_float(v.x & 0xffff0000u);
        a2 += __uint_as_float(v.y << 16);
        a3 += __uint_as_float(v.y & 0xffff0000u);
        a4 += __uint_as_float(v.z << 16);
        a5 += __uint_as_float(v.z & 0xffff0000u);
        a6 += __uint_as_float(v.w << 16);
        a7 += __uint_as_float(v.w & 0xffff0000u);
      }
    }
  }
  // combine 4 edge-subslots (lane bits 3..4) — stays within each half
#pragma unroll
  for (int off = 8; off <= 16; off <<= 1) {
    a0 += __shfl_xor(a0, off); a1 += __shfl_xor(a1, off);
    a2 += __shfl_xor(a2, off); a3 += __shfl_xor(a3, off);
    a4 += __shfl_xor(a4, off); a5 += __shfl_xor(a5, off);
    a6 += __shfl_xor(a6, off); a7 += __shfl_xor(a7, off);
  }
  {  // self-loop row (per-lane address by half's node)
    uint4 v = m1q[(size_t)node * 8 + q];
    a0 += __uint_as_float(v.x << 16);
    a1 += __uint_as_float(v.x & 0xffff0000u);
    a2 += __uint_as_float(v.y << 16);
    a3 += __uint_as_float(v.y & 0xffff0000u);
    a4 += __uint_as_float(v.z << 16);
    a5 += __uint_as_float(v.z & 0xffff0000u);
    a6 += __uint_as_float(v.w << 16);
    a7 += __uint_as_float(v.w & 0xffff0000u);
  }
  const float dv = dinv[node];
  const float4 bva = ((const float4*)b1)[q * 2 + 0];   // b1[8q..8q+3]
  const float4 bvb = ((const float4*)b1)[q * 2 + 1];   // b1[8q+4..8q+7]
  // W2[64][2] row-major: float4 i covers rows 2i,2i+1. Rows 8q..8q+7 = idx 4q..4q+3.
  const float4 wA = ((const float4*)W2)[q * 4 + 0];
  const float4 wB = ((const float4*)W2)[q * 4 + 1];
  const float4 wC = ((const float4*)W2)[q * 4 + 2];
  const float4 wD = ((const float4*)W2)[q * 4 + 3];
  float h0 = fmaxf(fmaf(a0, dv, bva.x), 0.f);
  float h1 = fmaxf(fmaf(a1, dv, bva.y), 0.f);
  float h2 = fmaxf(fmaf(a2, dv, bva.z), 0.f);
  float h3 = fmaxf(fmaf(a3, dv, bva.w), 0.f);
  float h4 = fmaxf(fmaf(a4, dv, bvb.x), 0.f);
  float h5 = fmaxf(fmaf(a5, dv, bvb.y), 0.f);
  float h6 = fmaxf(fmaf(a6, dv, bvb.z), 0.f);
  float h7 = fmaxf(fmaf(a7, dv, bvb.w), 0.f);
  float p0 = h0 * wA.x + h1 * wA.z + h2 * wB.x + h3 * wB.z
           + h4 * wC.x + h5 * wC.z + h6 * wD.x + h7 * wD.z;
  float p1 = h0 * wA.y + h1 * wA.w + h2 * wB.y + h3 * wB.w
           + h4 * wC.y + h5 * wC.w + h6 * wD.y + h7 * wD.w;
#pragma unroll
  for (int off = 4; off; off >>= 1) {  // reduce over q (lane bits 0..2)
    p0 += __shfl_xor(p0, off);
    p1 += __shfl_xor(p1, off);
  }
  if ((lane & 31) == 0) {              // lane 0 -> node A, lane 32 -> node B
    m2[node * 2 + 0] = p0 * dv;
    m2[node * 2 + 1] = p1 * dv;
  }
}

// ---- conv2: 2 nodes/wave light gather + bias + generator mask ----
__global__ __launch_bounds__(256) void k_agg2(const float* __restrict__ m2,
                                              const int* __restrict__ rowptr,
                                              const int* __restrict__ csr_src,
                                              const float* __restrict__ dinv,
                                              const float* __restrict__ b2,
                                              const float* __restrict__ x,
                                              float* __restrict__ out) {
  const int lane = threadIdx.x & 63;
  const int half = lane >> 5;
  const int node = blockIdx.x * 8 + (threadIdx.x >> 6) * 2 + half;  // exact grid
  const int s0 = rowptr[node];
  const int e0 = rowptr[node + 1];
  float a0 = 0.f, a1 = 0.f;
  for (int e = s0 + (lane & 31); e < e0; e += 32) {
    int s = csr_src[e];
    a0 += m2[s * 2 + 0];
    a1 += m2[s * 2 + 1];
  }
#pragma unroll
  for (int off = 16; off; off >>= 1) {   // reduce within half
    a0 += __shfl_xor(a0, off);
    a1 += __shfl_xor(a1, off);
  }
  if ((lane & 31) == 0) {
    a0 += m2[node * 2 + 0];  // self-loop
    a1 += m2[node * 2 + 1];
    float dv = dinv[node];
    float o0 = a0 * dv + b2[0];
    float o1 = a1 * dv + b2[1];
    float msk = (x[(size_t)node * FIN] == 1.0f) ? 1.0f : 0.0f;
    out[node * 2 + 0] = o0 * msk;
    out[node * 2 + 1] = o1 * msk;
  }
}

extern "C" void kernel_launch(void* const* d_in, const int* in_sizes, int n_in,
                              void* d_out, int out_size, void* d_ws, size_t ws_size,
                              hipStream_t stream) {
  const float* x   = (const float*)d_in[0];
  const int*   ei  = (const int*)d_in[1];  // int32 [2, E] flat
  const float* W1  = (const float*)d_in[2];
  const float* b1  = (const float*)d_in[3];
  const float* W2  = (const float*)d_in[4];
  const float* b2  = (const float*)d_in[5];
  float*       out = (float*)d_out;

  char* w = (char*)d_ws;
  auto alloc = [&](size_t bytes) -> char* {
    char* p = w;
    w += (bytes + 255) & ~(size_t)255;
    return p;
  };
  int*            rowptr  = (int*)alloc((size_t)(N + 1) * 4);
  float*          dinv    = (float*)alloc((size_t)N * 4);
  unsigned*       binned  = (unsigned*)alloc((size_t)E * 4);
  int*            segCnt  = (int*)alloc((size_t)NB * NC * 4);
  int*            lp      = (int*)alloc((size_t)NB * NC * 4);
  int*            binTot  = (int*)alloc((size_t)NB * 4);
  int*            binBase = (int*)alloc((size_t)(NB + 1) * 4);
  int*            csr_src = (int*)alloc((size_t)E * 4);
  __hip_bfloat16* m1      = (__hip_bfloat16*)alloc((size_t)N * FH * 2);
  float*          m2      = (float*)alloc((size_t)N * 2 * 4);

  const int* srcA = ei;      // edge_index[0]
  const int* dstA = ei + E;  // edge_index[1]

  k_cnt<<<dim3(NC), dim3(512), 0, stream>>>(dstA, segCnt);
  k_chunkScan<<<dim3(NB), dim3(512), 0, stream>>>(segCnt, lp, binTot);
  k_binScan<<<dim3(1), dim3(64), 0, stream>>>(binTot, binBase, rowptr);
  k_scat<<<dim3(NC), dim3(512), 0, stream>>>(srcA, dstA, lp, binBase, binned);
  k_fill4<<<dim3(NB), dim3(512), 0, stream>>>(binned, binBase, rowptr, dinv, csr_src);
  k_gemm1<<<dim3(800), dim3(256), 0, stream>>>(x, W1, dinv, m1);  // grid-stride tiles
  k_agg1<<<dim3(N / 8), dim3(256), 0, stream>>>(m1, rowptr, csr_src, dinv, b1, W2, m2);  // 12500
  k_agg2<<<dim3(N / 8), dim3(256), 0, stream>>>(m2, rowptr, csr_src, dinv, b2, x, out);  // 12500
}

// Round 12
// 137.805 us; speedup vs baseline: 12.4050x; 1.0572x over previous
//
#include <hip/hip_runtime.h>
#include <hip/hip_bf16.h>
#include <math.h>

// GCN 2-layer forward on MI355X — v12.
// v11 post-mortem: k_scat (46us) writes 60MB for a 12.8MB array — per-chunk
// window slices are ~1 cache line and adjacent chunks run on different XCDs
// (non-coherent L2s) => boundary-line ping-pong via HBM. v12: bijective
// XCD-aware chunk swizzle (each XCD owns a contiguous chunk run) for
// k_cnt/k_scat. Everything else unchanged.
// Pipeline: cnt -> chunkScan -> binScan -> scat -> fill4 -> gemm1(MFMA) ->
//           agg1 -> agg2.

constexpr int N   = 100000;
constexpr int E   = 3200000;
constexpr int FIN = 128;
constexpr int FH  = 64;

constexpr int NPB = 256;                      // nodes per bin
constexpr int NB  = (N + NPB - 1) / NPB;      // 391 bins
constexpr int K   = 6400;                     // edges per chunk
constexpr int NC  = E / K;                    // 500 chunks (exact)
constexpr int NXCD = 8;

typedef __attribute__((ext_vector_type(8))) short short8;   // 8 bf16 (4 VGPR)
typedef __attribute__((ext_vector_type(4))) float f32x4;    // MFMA acc

__device__ inline short f2bf(float f) {       // f32 -> bf16 (round-nearest-even)
  unsigned u = __float_as_uint(f);
  return (short)((u + 0x7FFFu + ((u >> 16) & 1u)) >> 16);
}

// Bijective XCD swizzle: HW round-robins blockIdx%8 -> XCD; remap so each XCD
// processes a CONTIGUOUS run of chunks (adjacent slices stay in one L2).
__device__ inline int chunk_of(int bid) {
  const int q = NC / NXCD, r = NC % NXCD;     // 62, 4
  int xcd = bid & 7, idx = bid >> 3;
  return (xcd < r) ? xcd * (q + 1) + idx : r * (q + 1) + (xcd - r) * q + idx;
}

// ---- 1: per-(chunk,bin) counts, bin-major layout ----
__global__ __launch_bounds__(512) void k_cnt(const int* __restrict__ dstA,
                                             int* __restrict__ segCnt) {
  __shared__ int bc[NB];
  const int w = chunk_of(blockIdx.x);
  const int base = w * K;
  for (int i = threadIdx.x; i < NB; i += 512) bc[i] = 0;
  __syncthreads();
  for (int i = threadIdx.x; i < K; i += 512)
    atomicAdd(&bc[dstA[base + i] >> 8], 1);
  __syncthreads();
  for (int b = threadIdx.x; b < NB; b += 512) segCnt[b * NC + w] = bc[b];
}

// ---- 2: per-bin exclusive scan over chunks -> lp, binTot ----
__global__ __launch_bounds__(512) void k_chunkScan(const int* __restrict__ segCnt,
                                                   int* __restrict__ lp,
                                                   int* __restrict__ binTot) {
  __shared__ int sh[512];
  const int b = blockIdx.x;
  const int t = threadIdx.x;
  int v = (t < NC) ? segCnt[b * NC + t] : 0;
  sh[t] = v;
  __syncthreads();
  for (int off = 1; off < 512; off <<= 1) {
    int tv = (t >= off) ? sh[t - off] : 0;
    __syncthreads();
    sh[t] += tv;
    __syncthreads();
  }
  if (t < NC) lp[b * NC + t] = sh[t] - v;   // exclusive prefix
  if (t == 511) binTot[b] = sh[511];
}

// ---- 3: tiny serial scan over 391 bins ----
__global__ void k_binScan(const int* __restrict__ binTot,
                          int* __restrict__ binBase, int* __restrict__ rowptr) {
  if (threadIdx.x == 0 && blockIdx.x == 0) {
    int s = 0;
    for (int b = 0; b < NB; ++b) { binBase[b] = s; s += binTot[b]; }
    binBase[NB] = s;
    rowptr[N] = s;  // == E
  }
}

// ---- 4: scatter edges into contiguous bin-major windows ----
__global__ __launch_bounds__(512) void k_scat(const int* __restrict__ srcA,
                                              const int* __restrict__ dstA,
                                              const int* __restrict__ lp,
                                              const int* __restrict__ binBase,
                                              unsigned* __restrict__ binned) {
  __shared__ int lpw[NB];
  __shared__ int cur[NB];
  const int w = chunk_of(blockIdx.x);
  const int base = w * K;
  for (int b = threadIdx.x; b < NB; b += 512) {
    lpw[b] = binBase[b] + lp[b * NC + w];
    cur[b] = 0;
  }
  __syncthreads();
  for (int i = threadIdx.x; i < K; i += 512) {
    int s = srcA[base + i];
    int d = dstA[base + i];
    int b = d >> 8;
    int slot = lpw[b] + atomicAdd(&cur[b], 1);  // adjacent slices same-XCD now
    binned[slot] = ((unsigned)(d & 255) << 17) | (unsigned)s;  // src<2^17, dl<2^8
  }
}

// ---- 5: per-bin CSR from contiguous window: count, scan, place ----
__global__ __launch_bounds__(512) void k_fill4(const unsigned* __restrict__ binned,
                                               const int* __restrict__ binBase,
                                               int* __restrict__ rowptr,
                                               float* __restrict__ dinv,
                                               int* __restrict__ csr_src) {
  __shared__ int cnt_s[NPB];
  __shared__ int sh[NPB];
  __shared__ int cur[NPB];
  const int b = blockIdx.x;
  const int t = threadIdx.x;
  const int w0 = binBase[b], w1 = binBase[b + 1];
  if (t < NPB) cnt_s[t] = 0;
  __syncthreads();
  for (int i = w0 + t; i < w1; i += 512)     // dense coalesced stream
    atomicAdd(&cnt_s[binned[i] >> 17], 1);
  __syncthreads();
  int v = 0;
  if (t < NPB) { v = cnt_s[t]; sh[t] = v; }
  __syncthreads();
  for (int off = 1; off < NPB; off <<= 1) {  // Hillis-Steele inclusive
    int tv = (t < NPB && t >= off) ? sh[t - off] : 0;
    __syncthreads();
    if (t < NPB) sh[t] += tv;
    __syncthreads();
  }
  if (t < NPB) {
    int node = b * NPB + t;
    int start = w0 + sh[t] - v;              // exclusive prefix within window
    if (node < N) {
      rowptr[node] = start;
      dinv[node] = 1.0f / sqrtf((float)(v + 1));  // +1 self-loop
    }
    cur[t] = start;
  }
  __syncthreads();
  for (int i = w0 + t; i < w1; i += 512) {   // re-read (L2-hot), place by node
    unsigned e = binned[i];
    int p = atomicAdd(&cur[e >> 17], 1);
    csr_src[p] = (int)(e & 0x1FFFFu);        // scatter confined to ~33KB window
  }
}

// ---- m1 = bf16((x @ W1) * dinv) via MFMA; wave = 16-node tile ----
__global__ __launch_bounds__(256) void k_gemm1(const float* __restrict__ x,
                                               const float* __restrict__ W1,
                                               const float* __restrict__ dinv,
                                               __hip_bfloat16* __restrict__ m1) {
  // B-fragments of W1 in LDS, frag-major: frag (s*4+j), lane l holds
  // W1[32s + 8*(l>>4) + e][16j + (l&15)] as bf16x8 -> ds_read_b128.
  __shared__ short8 W1f[16 * 64];  // 16 KB
  const int t = threadIdx.x;
  for (int i = t; i < 16 * 64; i += 256) {
    int frag = i >> 6, l = i & 63;
    int s = frag >> 2, j = frag & 3;
    int kb = 32 * s + 8 * (l >> 4);
    int f  = 16 * j + (l & 15);
    short8 v;
#pragma unroll
    for (int e = 0; e < 8; ++e) v[e] = f2bf(W1[(kb + e) * FH + f]);
    W1f[i] = v;
  }
  __syncthreads();
  const int lane = t & 63;
  const int r16 = lane & 15;   // A row within tile / D col
  const int g4  = lane >> 4;   // k-group
  const int nWaves = gridDim.x * 4;
  const int wid = blockIdx.x * 4 + (t >> 6);
  unsigned short* __restrict__ m1u = (unsigned short*)m1;
  for (int T = wid; T < N / 16; T += nWaves) {
    const float* xrow = x + (size_t)(16 * T + r16) * FIN + 8 * g4;
    f32x4 acc0 = {0,0,0,0}, acc1 = {0,0,0,0}, acc2 = {0,0,0,0}, acc3 = {0,0,0,0};
#pragma unroll
    for (int s = 0; s < 4; ++s) {
      float4 fa = *(const float4*)(xrow + 32 * s);       // coalesced, vmcnt-pipelined
      float4 fb = *(const float4*)(xrow + 32 * s + 4);
      short8 a;
      a[0] = f2bf(fa.x); a[1] = f2bf(fa.y); a[2] = f2bf(fa.z); a[3] = f2bf(fa.w);
      a[4] = f2bf(fb.x); a[5] = f2bf(fb.y); a[6] = f2bf(fb.z); a[7] = f2bf(fb.w);
      acc0 = __builtin_amdgcn_mfma_f32_16x16x32_bf16(a, W1f[(s*4+0)*64 + lane], acc0, 0, 0, 0);
      acc1 = __builtin_amdgcn_mfma_f32_16x16x32_bf16(a, W1f[(s*4+1)*64 + lane], acc1, 0, 0, 0);
      acc2 = __builtin_amdgcn_mfma_f32_16x16x32_bf16(a, W1f[(s*4+2)*64 + lane], acc2, 0, 0, 0);
      acc3 = __builtin_amdgcn_mfma_f32_16x16x32_bf16(a, W1f[(s*4+3)*64 + lane], acc3, 0, 0, 0);
    }
    // D layout: col = lane&15, row = 4*(lane>>4)+reg  [verified mapping]
    const int nodeBase = 16 * T + 4 * g4;
    float dv0 = dinv[nodeBase + 0];
    float dv1 = dinv[nodeBase + 1];
    float dv2 = dinv[nodeBase + 2];
    float dv3 = dinv[nodeBase + 3];
#pragma unroll
    for (int j = 0; j < 4; ++j) {
      f32x4 acc = (j == 0) ? acc0 : (j == 1) ? acc1 : (j == 2) ? acc2 : acc3;
      size_t fcol = 16 * j + r16;
      m1u[(size_t)(nodeBase + 0) * FH + fcol] = (unsigned short)f2bf(acc[0] * dv0);
      m1u[(size_t)(nodeBase + 1) * FH + fcol] = (unsigned short)f2bf(acc[1] * dv1);
      m1u[(size_t)(nodeBase + 2) * FH + fcol] = (unsigned short)f2bf(acc[2] * dv2);
      m1u[(size_t)(nodeBase + 3) * FH + fcol] = (unsigned short)f2bf(acc[3] * dv3);
    }
  }
}

// ---- conv1: 2 nodes/wave (one per 32-lane half), 8 edges per wave-load ----
__global__ __launch_bounds__(256) void k_agg1(const __hip_bfloat16* __restrict__ m1,
                                              const int* __restrict__ rowptr,
                                              const int* __restrict__ csr_src,
                                              const float* __restrict__ dinv,
                                              const float* __restrict__ b1,
                                              const float* __restrict__ W2,
                                              float* __restrict__ m2) {
  const int lane = threadIdx.x & 63;
  const int half = lane >> 5;                 // 0 = node A, 1 = node B
  const int node = blockIdx.x * 8 + (threadIdx.x >> 6) * 2 + half;  // exact grid
  const int g2 = (lane >> 3) & 3;             // edge subslot 0..3 within half
  const int q  = lane & 7;                    // uint4 index -> features 8q..8q+7
  const int s0 = rowptr[node];                // uniform per half
  const int deg = rowptr[node + 1] - s0;
  const uint4* __restrict__ m1q = (const uint4*)m1;  // row = 8 uint4 (128B)
  float a0=0.f,a1=0.f,a2=0.f,a3=0.f,a4=0.f,a5=0.f,a6=0.f,a7=0.f;
  const int i = lane & 31;                    // id slot within half's batch
  for (int base = 0;; base += 32) {
    int rem = deg - base;                     // uniform per half
    if (__all(rem <= 0)) break;
    int sv = (i < rem) ? csr_src[s0 + base + i] : 0;  // 32 ids per node
#pragma unroll
    for (int j = 0; j < 32; j += 8) {
      int idx = j + g2;
      int s = __shfl(sv, (half << 5) | idx);  // id from own half
      if (idx < rem) {                        // near-uniform predicate
        uint4 v = m1q[(size_t)s * 8 + q];     // 1 load = 8 edge-rows/wave
        a0 += __uint_as_float(v.x << 16);
        a1 += __uint_as_float(v.x & 0xffff0000u);
        a2 += __uint_as_float(v.y << 16);
        a3 += __uint_as_float(v.y & 0xffff0000u);
        a4 += __uint_as_float(v.z << 16);
        a5 += __uint_as_float(v.z & 0xffff0000u);
        a6 += __uint_as_float(v.w << 16);
        a7 += __uint_as_float(v.w & 0xffff0000u);
      }
    }
  }
  // combine 4 edge-subslots (lane bits 3..4) — stays within each half
#pragma unroll
  for (int off = 8; off <= 16; off <<= 1) {
    a0 += __shfl_xor(a0, off); a1 += __shfl_xor(a1, off);
    a2 += __shfl_xor(a2, off); a3 += __shfl_xor(a3, off);
    a4 += __shfl_xor(a4, off); a5 += __shfl_xor(a5, off);
    a6 += __shfl_xor(a6, off); a7 += __shfl_xor(a7, off);
  }
  {  // self-loop row (per-lane address by half's node)
    uint4 v = m1q[(size_t)node * 8 + q];
    a0 += __uint_as_float(v.x << 16);
    a1 += __uint_as_float(v.x & 0xffff0000u);
    a2 += __uint_as_float(v.y << 16);
    a3 += __uint_as_float(v.y & 0xffff0000u);
    a4 += __uint_as_float(v.z << 16);
    a5 += __uint_as_float(v.z & 0xffff0000u);
    a6 += __uint_as_float(v.w << 16);
    a7 += __uint_as_float(v.w & 0xffff0000u);
  }
  const float dv = dinv[node];
  const float4 bva = ((const float4*)b1)[q * 2 + 0];   // b1[8q..8q+3]
  const float4 bvb = ((const float4*)b1)[q * 2 + 1];   // b1[8q+4..8q+7]
  // W2[64][2] row-major: float4 i covers rows 2i,2i+1. Rows 8q..8q+7 = idx 4q..4q+3.
  const float4 wA = ((const float4*)W2)[q * 4 + 0];
  const float4 wB = ((const float4*)W2)[q * 4 + 1];
  const float4 wC = ((const float4*)W2)[q * 4 + 2];
  const float4 wD = ((const float4*)W2)[q * 4 + 3];
  float h0 = fmaxf(fmaf(a0, dv, bva.x), 0.f);
  float h1 = fmaxf(fmaf(a1, dv, bva.y), 0.f);
  float h2 = fmaxf(fmaf(a2, dv, bva.z), 0.f);
  float h3 = fmaxf(fmaf(a3, dv, bva.w), 0.f);
  float h4 = fmaxf(fmaf(a4, dv, bvb.x), 0.f);
  float h5 = fmaxf(fmaf(a5, dv, bvb.y), 0.f);
  float h6 = fmaxf(fmaf(a6, dv, bvb.z), 0.f);
  float h7 = fmaxf(fmaf(a7, dv, bvb.w), 0.f);
  float p0 = h0 * wA.x + h1 * wA.z + h2 * wB.x + h3 * wB.z
           + h4 * wC.x + h5 * wC.z + h6 * wD.x + h7 * wD.z;
  float p1 = h0 * wA.y + h1 * wA.w + h2 * wB.y + h3 * wB.w
           + h4 * wC.y + h5 * wC.w + h6 * wD.y + h7 * wD.w;
#pragma unroll
  for (int off = 4; off; off >>= 1) {  // reduce over q (lane bits 0..2)
    p0 += __shfl_xor(p0, off);
    p1 += __shfl_xor(p1, off);
  }
  if ((lane & 31) == 0) {              // lane 0 -> node A, lane 32 -> node B
    m2[node * 2 + 0] = p0 * dv;
    m2[node * 2 + 1] = p1 * dv;
  }
}

// ---- conv2: 2 nodes/wave light gather + bias + generator mask ----
__global__ __launch_bounds__(256) void k_agg2(const float* __restrict__ m2,
                                              const int* __restrict__ rowptr,
                                              const int* __restrict__ csr_src,
                                              const float* __restrict__ dinv,
                                              const float* __restrict__ b2,
                                              const float* __restrict__ x,
                                              float* __restrict__ out) {
  const int lane = threadIdx.x & 63;
  const int half = lane >> 5;
  const int node = blockIdx.x * 8 + (threadIdx.x >> 6) * 2 + half;  // exact grid
  const int s0 = rowptr[node];
  const int e0 = rowptr[node + 1];
  float a0 = 0.f, a1 = 0.f;
  for (int e = s0 + (lane & 31); e < e0; e += 32) {
    int s = csr_src[e];
    a0 += m2[s * 2 + 0];
    a1 += m2[s * 2 + 1];
  }
#pragma unroll
  for (int off = 16; off; off >>= 1) {   // reduce within half
    a0 += __shfl_xor(a0, off);
    a1 += __shfl_xor(a1, off);
  }
  if ((lane & 31) == 0) {
    a0 += m2[node * 2 + 0];  // self-loop
    a1 += m2[node * 2 + 1];
    float dv = dinv[node];
    float o0 = a0 * dv + b2[0];
    float o1 = a1 * dv + b2[1];
    float msk = (x[(size_t)node * FIN] == 1.0f) ? 1.0f : 0.0f;
    out[node * 2 + 0] = o0 * msk;
    out[node * 2 + 1] = o1 * msk;
  }
}

extern "C" void kernel_launch(void* const* d_in, const int* in_sizes, int n_in,
                              void* d_out, int out_size, void* d_ws, size_t ws_size,
                              hipStream_t stream) {
  const float* x   = (const float*)d_in[0];
  const int*   ei  = (const int*)d_in[1];  // int32 [2, E] flat
  const float* W1  = (const float*)d_in[2];
  const float* b1  = (const float*)d_in[3];
  const float* W2  = (const float*)d_in[4];
  const float* b2  = (const float*)d_in[5];
  float*       out = (float*)d_out;

  char* w = (char*)d_ws;
  auto alloc = [&](size_t bytes) -> char* {
    char* p = w;
    w += (bytes + 255) & ~(size_t)255;
    return p;
  };
  int*            rowptr  = (int*)alloc((size_t)(N + 1) * 4);
  float*          dinv    = (float*)alloc((size_t)N * 4);
  unsigned*       binned  = (unsigned*)alloc((size_t)E * 4);
  int*            segCnt  = (int*)alloc((size_t)NB * NC * 4);
  int*            lp      = (int*)alloc((size_t)NB * NC * 4);
  int*            binTot  = (int*)alloc((size_t)NB * 4);
  int*            binBase = (int*)alloc((size_t)(NB + 1) * 4);
  int*            csr_src = (int*)alloc((size_t)E * 4);
  __hip_bfloat16* m1      = (__hip_bfloat16*)alloc((size_t)N * FH * 2);
  float*          m2      = (float*)alloc((size_t)N * 2 * 4);

  const int* srcA = ei;      // edge_index[0]
  const int* dstA = ei + E;  // edge_index[1]

  k_cnt<<<dim3(NC), dim3(512), 0, stream>>>(dstA, segCnt);
  k_chunkScan<<<dim3(NB), dim3(512), 0, stream>>>(segCnt, lp, binTot);
  k_binScan<<<dim3(1), dim3(64), 0, stream>>>(binTot, binBase, rowptr);
  k_scat<<<dim3(NC), dim3(512), 0, stream>>>(srcA, dstA, lp, binBase, binned);
  k_fill4<<<dim3(NB), dim3(512), 0, stream>>>(binned, binBase, rowptr, dinv, csr_src);
  k_gemm1<<<dim3(800), dim3(256), 0, stream>>>(x, W1, dinv, m1);  // grid-stride tiles
  k_agg1<<<dim3(N / 8), dim3(256), 0, stream>>>(m1, rowptr, csr_src, dinv, b1, W2, m2);  // 12500
  k_agg2<<<dim3(N / 8), dim3(256), 0, stream>>>(m2, rowptr, csr_src, dinv, b2, x, out);  // 12500
}

// Round 13
// 136.882 us; speedup vs baseline: 12.4887x; 1.0067x over previous
//
#include <hip/hip_runtime.h>
#include <hip/hip_bf16.h>
#include <math.h>

// GCN 2-layer forward on MI355X — v13.
// v12 post-mortem: k_agg1 (41.5us) half latency-exposed: only 4 gathers in
// flight/wave (deg~32 => 1 batch). v13: 4 nodes/wave, 2 independent gather
// streams => 8 loads in flight. fill4: single-pass (window held in regs).
// Pipeline: cnt -> chunkScan -> binScan -> scat -> fill4 -> gemm1(MFMA) ->
//           agg1 -> agg2.

constexpr int N   = 100000;
constexpr int E   = 3200000;
constexpr int FIN = 128;
constexpr int FH  = 64;

constexpr int NPB = 256;                      // nodes per bin
constexpr int NB  = (N + NPB - 1) / NPB;      // 391 bins
constexpr int K   = 6400;                     // edges per chunk
constexpr int NC  = E / K;                    // 500 chunks (exact)
constexpr int NXCD = 8;

typedef __attribute__((ext_vector_type(8))) short short8;   // 8 bf16 (4 VGPR)
typedef __attribute__((ext_vector_type(4))) float f32x4;    // MFMA acc

__device__ inline short f2bf(float f) {       // f32 -> bf16 (round-nearest-even)
  unsigned u = __float_as_uint(f);
  return (short)((u + 0x7FFFu + ((u >> 16) & 1u)) >> 16);
}

// Bijective XCD swizzle: each XCD owns a contiguous run of chunks.
__device__ inline int chunk_of(int bid) {
  const int q = NC / NXCD, r = NC % NXCD;     // 62, 4
  int xcd = bid & 7, idx = bid >> 3;
  return (xcd < r) ? xcd * (q + 1) + idx : r * (q + 1) + (xcd - r) * q + idx;
}

// ---- 1: per-(chunk,bin) counts, bin-major layout ----
__global__ __launch_bounds__(512) void k_cnt(const int* __restrict__ dstA,
                                             int* __restrict__ segCnt) {
  __shared__ int bc[NB];
  const int w = chunk_of(blockIdx.x);
  const int base = w * K;
  for (int i = threadIdx.x; i < NB; i += 512) bc[i] = 0;
  __syncthreads();
  for (int i = threadIdx.x; i < K; i += 512)
    atomicAdd(&bc[dstA[base + i] >> 8], 1);
  __syncthreads();
  for (int b = threadIdx.x; b < NB; b += 512) segCnt[b * NC + w] = bc[b];
}

// ---- 2: per-bin exclusive scan over chunks -> lp, binTot ----
__global__ __launch_bounds__(512) void k_chunkScan(const int* __restrict__ segCnt,
                                                   int* __restrict__ lp,
                                                   int* __restrict__ binTot) {
  __shared__ int sh[512];
  const int b = blockIdx.x;
  const int t = threadIdx.x;
  int v = (t < NC) ? segCnt[b * NC + t] : 0;
  sh[t] = v;
  __syncthreads();
  for (int off = 1; off < 512; off <<= 1) {
    int tv = (t >= off) ? sh[t - off] : 0;
    __syncthreads();
    sh[t] += tv;
    __syncthreads();
  }
  if (t < NC) lp[b * NC + t] = sh[t] - v;   // exclusive prefix
  if (t == 511) binTot[b] = sh[511];
}

// ---- 3: tiny serial scan over 391 bins ----
__global__ void k_binScan(const int* __restrict__ binTot,
                          int* __restrict__ binBase, int* __restrict__ rowptr) {
  if (threadIdx.x == 0 && blockIdx.x == 0) {
    int s = 0;
    for (int b = 0; b < NB; ++b) { binBase[b] = s; s += binTot[b]; }
    binBase[NB] = s;
    rowptr[N] = s;  // == E
  }
}

// ---- 4: scatter edges into contiguous bin-major windows ----
__global__ __launch_bounds__(512) void k_scat(const int* __restrict__ srcA,
                                              const int* __restrict__ dstA,
                                              const int* __restrict__ lp,
                                              const int* __restrict__ binBase,
                                              unsigned* __restrict__ binned) {
  __shared__ int lpw[NB];
  __shared__ int cur[NB];
  const int w = chunk_of(blockIdx.x);
  const int base = w * K;
  for (int b = threadIdx.x; b < NB; b += 512) {
    lpw[b] = binBase[b] + lp[b * NC + w];
    cur[b] = 0;
  }
  __syncthreads();
  for (int i = threadIdx.x; i < K; i += 512) {
    int s = srcA[base + i];
    int d = dstA[base + i];
    int b = d >> 8;
    int slot = lpw[b] + atomicAdd(&cur[b], 1);  // adjacent slices same-XCD
    binned[slot] = ((unsigned)(d & 255) << 17) | (unsigned)s;  // src<2^17, dl<2^8
  }
}

// ---- 5: per-bin CSR, single pass: window edges held in registers ----
__global__ __launch_bounds__(512) void k_fill4(const unsigned* __restrict__ binned,
                                               const int* __restrict__ binBase,
                                               int* __restrict__ rowptr,
                                               float* __restrict__ dinv,
                                               int* __restrict__ csr_src) {
  __shared__ int cnt_s[NPB];
  __shared__ int sh[NPB];
  __shared__ int cur[NPB];
  const int b = blockIdx.x;
  const int t = threadIdx.x;
  const int w0 = binBase[b], w1 = binBase[b + 1];
  if (t < NPB) cnt_s[t] = 0;
  __syncthreads();
  // window <= 17*512 = 8704 statistically (mean 8184, sd~90); fallback below.
  unsigned e0_,e1_,e2_,e3_,e4_,e5_,e6_,e7_,e8_,e9_,e10_,e11_,e12_,e13_,e14_,e15_,e16_;
  unsigned* ebuf[17] = {&e0_,&e1_,&e2_,&e3_,&e4_,&e5_,&e6_,&e7_,&e8_,&e9_,
                        &e10_,&e11_,&e12_,&e13_,&e14_,&e15_,&e16_};
#pragma unroll
  for (int r = 0; r < 17; ++r) {
    int i = w0 + t + r * 512;
    unsigned e = (i < w1) ? binned[i] : 0xFFFFFFFFu;
    *ebuf[r] = e;
    if (e != 0xFFFFFFFFu) atomicAdd(&cnt_s[e >> 17], 1);
  }
  for (int i = w0 + t + 17 * 512; i < w1; i += 512)   // overflow guard (no-op)
    atomicAdd(&cnt_s[binned[i] >> 17], 1);
  __syncthreads();
  int v = 0;
  if (t < NPB) { v = cnt_s[t]; sh[t] = v; }
  __syncthreads();
  for (int off = 1; off < NPB; off <<= 1) {  // Hillis-Steele inclusive
    int tv = (t < NPB && t >= off) ? sh[t - off] : 0;
    __syncthreads();
    if (t < NPB) sh[t] += tv;
    __syncthreads();
  }
  if (t < NPB) {
    int node = b * NPB + t;
    int start = w0 + sh[t] - v;              // exclusive prefix within window
    if (node < N) {
      rowptr[node] = start;
      dinv[node] = 1.0f / sqrtf((float)(v + 1));  // +1 self-loop
    }
    cur[t] = start;
  }
  __syncthreads();
#pragma unroll
  for (int r = 0; r < 17; ++r) {
    unsigned e = *ebuf[r];
    if (e != 0xFFFFFFFFu) {
      int p = atomicAdd(&cur[e >> 17], 1);
      csr_src[p] = (int)(e & 0x1FFFFu);      // scatter confined to ~33KB window
    }
  }
  for (int i = w0 + t + 17 * 512; i < w1; i += 512) {  // overflow guard (no-op)
    unsigned e = binned[i];
    int p = atomicAdd(&cur[e >> 17], 1);
    csr_src[p] = (int)(e & 0x1FFFFu);
  }
}

// ---- m1 = bf16((x @ W1) * dinv) via MFMA; wave = 16-node tile ----
__global__ __launch_bounds__(256) void k_gemm1(const float* __restrict__ x,
                                               const float* __restrict__ W1,
                                               const float* __restrict__ dinv,
                                               __hip_bfloat16* __restrict__ m1) {
  __shared__ short8 W1f[16 * 64];  // 16 KB, fragment-major
  const int t = threadIdx.x;
  for (int i = t; i < 16 * 64; i += 256) {
    int frag = i >> 6, l = i & 63;
    int s = frag >> 2, j = frag & 3;
    int kb = 32 * s + 8 * (l >> 4);
    int f  = 16 * j + (l & 15);
    short8 v;
#pragma unroll
    for (int e = 0; e < 8; ++e) v[e] = f2bf(W1[(kb + e) * FH + f]);
    W1f[i] = v;
  }
  __syncthreads();
  const int lane = t & 63;
  const int r16 = lane & 15;   // A row within tile / D col
  const int g4  = lane >> 4;   // k-group
  const int nWaves = gridDim.x * 4;
  const int wid = blockIdx.x * 4 + (t >> 6);
  unsigned short* __restrict__ m1u = (unsigned short*)m1;
  for (int T = wid; T < N / 16; T += nWaves) {
    const float* xrow = x + (size_t)(16 * T + r16) * FIN + 8 * g4;
    f32x4 acc0 = {0,0,0,0}, acc1 = {0,0,0,0}, acc2 = {0,0,0,0}, acc3 = {0,0,0,0};
#pragma unroll
    for (int s = 0; s < 4; ++s) {
      float4 fa = *(const float4*)(xrow + 32 * s);       // coalesced
      float4 fb = *(const float4*)(xrow + 32 * s + 4);
      short8 a;
      a[0] = f2bf(fa.x); a[1] = f2bf(fa.y); a[2] = f2bf(fa.z); a[3] = f2bf(fa.w);
      a[4] = f2bf(fb.x); a[5] = f2bf(fb.y); a[6] = f2bf(fb.z); a[7] = f2bf(fb.w);
      acc0 = __builtin_amdgcn_mfma_f32_16x16x32_bf16(a, W1f[(s*4+0)*64 + lane], acc0, 0, 0, 0);
      acc1 = __builtin_amdgcn_mfma_f32_16x16x32_bf16(a, W1f[(s*4+1)*64 + lane], acc1, 0, 0, 0);
      acc2 = __builtin_amdgcn_mfma_f32_16x16x32_bf16(a, W1f[(s*4+2)*64 + lane], acc2, 0, 0, 0);
      acc3 = __builtin_amdgcn_mfma_f32_16x16x32_bf16(a, W1f[(s*4+3)*64 + lane], acc3, 0, 0, 0);
    }
    const int nodeBase = 16 * T + 4 * g4;
    float dv0 = dinv[nodeBase + 0];
    float dv1 = dinv[nodeBase + 1];
    float dv2 = dinv[nodeBase + 2];
    float dv3 = dinv[nodeBase + 3];
#pragma unroll
    for (int j = 0; j < 4; ++j) {
      f32x4 acc = (j == 0) ? acc0 : (j == 1) ? acc1 : (j == 2) ? acc2 : acc3;
      size_t fcol = 16 * j + r16;
      m1u[(size_t)(nodeBase + 0) * FH + fcol] = (unsigned short)f2bf(acc[0] * dv0);
      m1u[(size_t)(nodeBase + 1) * FH + fcol] = (unsigned short)f2bf(acc[1] * dv1);
      m1u[(size_t)(nodeBase + 2) * FH + fcol] = (unsigned short)f2bf(acc[2] * dv2);
      m1u[(size_t)(nodeBase + 3) * FH + fcol] = (unsigned short)f2bf(acc[3] * dv3);
    }
  }
}

// ---- conv1: 4 nodes/wave, 2 independent gather streams (8 loads in flight) ----
__global__ __launch_bounds__(256) void k_agg1(const __hip_bfloat16* __restrict__ m1,
                                              const int* __restrict__ rowptr,
                                              const int* __restrict__ csr_src,
                                              const float* __restrict__ dinv,
                                              const float* __restrict__ b1,
                                              const float* __restrict__ W2,
                                              float* __restrict__ m2) {
  const int lane = threadIdx.x & 63;
  const int half = lane >> 5;
  const int nb   = blockIdx.x * 16 + (threadIdx.x >> 6) * 4;  // exact grid
  const int node0 = nb + half;        // stream 0: nodes nb, nb+1
  const int node1 = nb + 2 + half;    // stream 1: nodes nb+2, nb+3
  const int g2 = (lane >> 3) & 3;
  const int q  = lane & 7;
  const int i  = lane & 31;
  const int s00 = rowptr[node0];
  const int deg0 = rowptr[node0 + 1] - s00;
  const int s01 = rowptr[node1];
  const int deg1 = rowptr[node1 + 1] - s01;
  const uint4* __restrict__ m1q = (const uint4*)m1;  // row = 8 uint4 (128B)
  float x0=0,x1=0,x2=0,x3=0,x4=0,x5=0,x6=0,x7=0;     // stream 0 acc
  float y0=0,y1=0,y2=0,y3=0,y4=0,y5=0,y6=0,y7=0;     // stream 1 acc
  for (int base = 0;; base += 32) {
    int rem0 = deg0 - base, rem1 = deg1 - base;
    if (__all((rem0 <= 0) && (rem1 <= 0))) break;
    int sv0 = (i < rem0) ? csr_src[s00 + base + i] : 0;
    int sv1 = (i < rem1) ? csr_src[s01 + base + i] : 0;
#pragma unroll
    for (int j = 0; j < 32; j += 8) {
      int idx = j + g2;
      int sa = __shfl(sv0, (half << 5) | idx);
      int sb = __shfl(sv1, (half << 5) | idx);
      bool pa = idx < rem0, pb = idx < rem1;
      uint4 va, vb;
      if (pa) va = m1q[(size_t)sa * 8 + q];
      if (pb) vb = m1q[(size_t)sb * 8 + q];
      if (pa) {
        x0 += __uint_as_float(va.x << 16); x1 += __uint_as_float(va.x & 0xffff0000u);
        x2 += __uint_as_float(va.y << 16); x3 += __uint_as_float(va.y & 0xffff0000u);
        x4 += __uint_as_float(va.z << 16); x5 += __uint_as_float(va.z & 0xffff0000u);
        x6 += __uint_as_float(va.w << 16); x7 += __uint_as_float(va.w & 0xffff0000u);
      }
      if (pb) {
        y0 += __uint_as_float(vb.x << 16); y1 += __uint_as_float(vb.x & 0xffff0000u);
        y2 += __uint_as_float(vb.y << 16); y3 += __uint_as_float(vb.y & 0xffff0000u);
        y4 += __uint_as_float(vb.z << 16); y5 += __uint_as_float(vb.z & 0xffff0000u);
        y6 += __uint_as_float(vb.w << 16); y7 += __uint_as_float(vb.w & 0xffff0000u);
      }
    }
  }
  // combine 4 edge-subslots within each half, both streams
#pragma unroll
  for (int off = 8; off <= 16; off <<= 1) {
    x0 += __shfl_xor(x0, off); x1 += __shfl_xor(x1, off);
    x2 += __shfl_xor(x2, off); x3 += __shfl_xor(x3, off);
    x4 += __shfl_xor(x4, off); x5 += __shfl_xor(x5, off);
    x6 += __shfl_xor(x6, off); x7 += __shfl_xor(x7, off);
    y0 += __shfl_xor(y0, off); y1 += __shfl_xor(y1, off);
    y2 += __shfl_xor(y2, off); y3 += __shfl_xor(y3, off);
    y4 += __shfl_xor(y4, off); y5 += __shfl_xor(y5, off);
    y6 += __shfl_xor(y6, off); y7 += __shfl_xor(y7, off);
  }
  {  // self-loop rows
    uint4 va = m1q[(size_t)node0 * 8 + q];
    uint4 vb = m1q[(size_t)node1 * 8 + q];
    x0 += __uint_as_float(va.x << 16); x1 += __uint_as_float(va.x & 0xffff0000u);
    x2 += __uint_as_float(va.y << 16); x3 += __uint_as_float(va.y & 0xffff0000u);
    x4 += __uint_as_float(va.z << 16); x5 += __uint_as_float(va.z & 0xffff0000u);
    x6 += __uint_as_float(va.w << 16); x7 += __uint_as_float(va.w & 0xffff0000u);
    y0 += __uint_as_float(vb.x << 16); y1 += __uint_as_float(vb.x & 0xffff0000u);
    y2 += __uint_as_float(vb.y << 16); y3 += __uint_as_float(vb.y & 0xffff0000u);
    y4 += __uint_as_float(vb.z << 16); y5 += __uint_as_float(vb.z & 0xffff0000u);
    y6 += __uint_as_float(vb.w << 16); y7 += __uint_as_float(vb.w & 0xffff0000u);
  }
  const float4 bva = ((const float4*)b1)[q * 2 + 0];   // b1[8q..8q+3]
  const float4 bvb = ((const float4*)b1)[q * 2 + 1];   // b1[8q+4..8q+7]
  const float4 wA = ((const float4*)W2)[q * 4 + 0];    // W2 rows 8q..8q+7
  const float4 wB = ((const float4*)W2)[q * 4 + 1];
  const float4 wC = ((const float4*)W2)[q * 4 + 2];
  const float4 wD = ((const float4*)W2)[q * 4 + 3];
  const float dv0 = dinv[node0];
  const float dv1 = dinv[node1];
  // stream 0 epilogue
  float h0 = fmaxf(fmaf(x0, dv0, bva.x), 0.f);
  float h1 = fmaxf(fmaf(x1, dv0, bva.y), 0.f);
  float h2 = fmaxf(fmaf(x2, dv0, bva.z), 0.f);
  float h3 = fmaxf(fmaf(x3, dv0, bva.w), 0.f);
  float h4 = fmaxf(fmaf(x4, dv0, bvb.x), 0.f);
  float h5 = fmaxf(fmaf(x5, dv0, bvb.y), 0.f);
  float h6 = fmaxf(fmaf(x6, dv0, bvb.z), 0.f);
  float h7 = fmaxf(fmaf(x7, dv0, bvb.w), 0.f);
  float p00 = h0 * wA.x + h1 * wA.z + h2 * wB.x + h3 * wB.z
            + h4 * wC.x + h5 * wC.z + h6 * wD.x + h7 * wD.z;
  float p01 = h0 * wA.y + h1 * wA.w + h2 * wB.y + h3 * wB.w
            + h4 * wC.y + h5 * wC.w + h6 * wD.y + h7 * wD.w;
  // stream 1 epilogue
  h0 = fmaxf(fmaf(y0, dv1, bva.x), 0.f);
  h1 = fmaxf(fmaf(y1, dv1, bva.y), 0.f);
  h2 = fmaxf(fmaf(y2, dv1, bva.z), 0.f);
  h3 = fmaxf(fmaf(y3, dv1, bva.w), 0.f);
  h4 = fmaxf(fmaf(y4, dv1, bvb.x), 0.f);
  h5 = fmaxf(fmaf(y5, dv1, bvb.y), 0.f);
  h6 = fmaxf(fmaf(y6, dv1, bvb.z), 0.f);
  h7 = fmaxf(fmaf(y7, dv1, bvb.w), 0.f);
  float p10 = h0 * wA.x + h1 * wA.z + h2 * wB.x + h3 * wB.z
            + h4 * wC.x + h5 * wC.z + h6 * wD.x + h7 * wD.z;
  float p11 = h0 * wA.y + h1 * wA.w + h2 * wB.y + h3 * wB.w
            + h4 * wC.y + h5 * wC.w + h6 * wD.y + h7 * wD.w;
#pragma unroll
  for (int off = 4; off; off >>= 1) {  // reduce over q (lane bits 0..2)
    p00 += __shfl_xor(p00, off); p01 += __shfl_xor(p01, off);
    p10 += __shfl_xor(p10, off); p11 += __shfl_xor(p11, off);
  }
  if ((lane & 31) == 0) {
    m2[node0 * 2 + 0] = p00 * dv0;
    m2[node0 * 2 + 1] = p01 * dv0;
    m2[node1 * 2 + 0] = p10 * dv1;
    m2[node1 * 2 + 1] = p11 * dv1;
  }
}

// ---- conv2: 2 nodes/wave light gather + bias + generator mask ----
__global__ __launch_bounds__(256) void k_agg2(const float* __restrict__ m2,
                                              const int* __restrict__ rowptr,
                                              const int* __restrict__ csr_src,
                                              const float* __restrict__ dinv,
                                              const float* __restrict__ b2,
                                              const float* __restrict__ x,
                                              float* __restrict__ out) {
  const int lane = threadIdx.x & 63;
  const int half = lane >> 5;
  const int node = blockIdx.x * 8 + (threadIdx.x >> 6) * 2 + half;  // exact grid
  const int s0 = rowptr[node];
  const int e0 = rowptr[node + 1];
  float a0 = 0.f, a1 = 0.f;
  for (int e = s0 + (lane & 31); e < e0; e += 32) {
    int s = csr_src[e];
    a0 += m2[s * 2 + 0];
    a1 += m2[s * 2 + 1];
  }
#pragma unroll
  for (int off = 16; off; off >>= 1) {   // reduce within half
    a0 += __shfl_xor(a0, off);
    a1 += __shfl_xor(a1, off);
  }
  if ((lane & 31) == 0) {
    a0 += m2[node * 2 + 0];  // self-loop
    a1 += m2[node * 2 + 1];
    float dv = dinv[node];
    float o0 = a0 * dv + b2[0];
    float o1 = a1 * dv + b2[1];
    float msk = (x[(size_t)node * FIN] == 1.0f) ? 1.0f : 0.0f;
    out[node * 2 + 0] = o0 * msk;
    out[node * 2 + 1] = o1 * msk;
  }
}

extern "C" void kernel_launch(void* const* d_in, const int* in_sizes, int n_in,
                              void* d_out, int out_size, void* d_ws, size_t ws_size,
                              hipStream_t stream) {
  const float* x   = (const float*)d_in[0];
  const int*   ei  = (const int*)d_in[1];  // int32 [2, E] flat
  const float* W1  = (const float*)d_in[2];
  const float* b1  = (const float*)d_in[3];
  const float* W2  = (const float*)d_in[4];
  const float* b2  = (const float*)d_in[5];
  float*       out = (float*)d_out;

  char* w = (char*)d_ws;
  auto alloc = [&](size_t bytes) -> char* {
    char* p = w;
    w += (bytes + 255) & ~(size_t)255;
    return p;
  };
  int*            rowptr  = (int*)alloc((size_t)(N + 1) * 4);
  float*          dinv    = (float*)alloc((size_t)N * 4);
  unsigned*       binned  = (unsigned*)alloc((size_t)E * 4);
  int*            segCnt  = (int*)alloc((size_t)NB * NC * 4);
  int*            lp      = (int*)alloc((size_t)NB * NC * 4);
  int*            binTot  = (int*)alloc((size_t)NB * 4);
  int*            binBase = (int*)alloc((size_t)(NB + 1) * 4);
  int*            csr_src = (int*)alloc((size_t)E * 4);
  __hip_bfloat16* m1      = (__hip_bfloat16*)alloc((size_t)N * FH * 2);
  float*          m2      = (float*)alloc((size_t)N * 2 * 4);

  const int* srcA = ei;      // edge_index[0]
  const int* dstA = ei + E;  // edge_index[1]

  k_cnt<<<dim3(NC), dim3(512), 0, stream>>>(dstA, segCnt);
  k_chunkScan<<<dim3(NB), dim3(512), 0, stream>>>(segCnt, lp, binTot);
  k_binScan<<<dim3(1), dim3(64), 0, stream>>>(binTot, binBase, rowptr);
  k_scat<<<dim3(NC), dim3(512), 0, stream>>>(srcA, dstA, lp, binBase, binned);
  k_fill4<<<dim3(NB), dim3(512), 0, stream>>>(binned, binBase, rowptr, dinv, csr_src);
  k_gemm1<<<dim3(800), dim3(256), 0, stream>>>(x, W1, dinv, m1);  // grid-stride tiles
  k_agg1<<<dim3(N / 16), dim3(256), 0, stream>>>(m1, rowptr, csr_src, dinv, b1, W2, m2);
  k_agg2<<<dim3(N / 8), dim3(256), 0, stream>>>(m2, rowptr, csr_src, dinv, b2, x, out);
}